// Round 1
// baseline (673.727 us; speedup 1.0000x reference)
//
#include <hip/hip_runtime.h>
#include <hip/hip_cooperative_groups.h>
#include <math.h>

namespace cg = cooperative_groups;

#define EMB 128
#define MAXEV 4096

__device__ __forceinline__ float sigmoidf_(float x) {
    return 1.0f / (1.0f + expf(-x));
}

// ---------------------------------------------------------------------------
// Kernel 1: for each event t, find the most recent earlier event with the
// same user id (prev_u) and same item id (prev_i); -1 if none.
// One wave (64 threads) per event; lanes stride the history, wave-max reduce.
// ---------------------------------------------------------------------------
__global__ __launch_bounds__(64) void prev_kernel(
    const int* __restrict__ uids, const int* __restrict__ iids,
    int* __restrict__ prevu, int* __restrict__ previ, int nev)
{
    int t = blockIdx.x;
    if (t >= nev) return;
    int lane = threadIdx.x;
    int myu = uids[t], myi = iids[t];
    int bu = -1, bi = -1;
    for (int j = lane; j < t; j += 64) {
        if (uids[j] == myu) bu = j;  // j increasing => keeps max match for lane
        if (iids[j] == myi) bi = j;
    }
    for (int off = 32; off; off >>= 1) {
        bu = max(bu, __shfl_xor(bu, off));
        bi = max(bi, __shfl_xor(bi, off));
    }
    if (lane == 0) { prevu[t] = bu; previ[t] = bi; }
}

// ---------------------------------------------------------------------------
// Kernel 2 (single block): DAG longest-path levels via relaxation in LDS,
// then counting-sort events by level. Events within a level are independent
// (same-id events are forced into strictly increasing levels).
// ---------------------------------------------------------------------------
__global__ __launch_bounds__(1024) void level_kernel(
    const int* __restrict__ prevu, const int* __restrict__ previ,
    int* __restrict__ order, int* __restrict__ offs,
    int* __restrict__ nlev_out, int nev)
{
    __shared__ int   spu[MAXEV];
    __shared__ int   spi[MAXEV];
    __shared__ short slev[MAXEV];
    __shared__ int   scnt[MAXEV + 1];
    __shared__ int   schanged;
    __shared__ int   smax;

    int tid = threadIdx.x;
    for (int t = tid; t < nev; t += 1024) {
        spu[t] = prevu[t];
        spi[t] = previ[t];
        slev[t] = 0;
    }
    __syncthreads();

    // Bellman-Ford-style relaxation; monotone, converges in DAG-depth iters.
    for (int it = 0; it < nev; ++it) {
        if (tid == 0) schanged = 0;
        __syncthreads();
        for (int t = tid; t < nev; t += 1024) {
            int pu = spu[t], pi = spi[t];
            int nl = 0;
            if (pu >= 0) nl = slev[pu] + 1;
            if (pi >= 0) { int c = slev[pi] + 1; nl = nl > c ? nl : c; }
            if (nl > (int)slev[t]) { slev[t] = (short)nl; schanged = 1; }
        }
        __syncthreads();
        if (!schanged) break;
    }

    if (tid == 0) smax = 0;
    __syncthreads();
    int lm = 0;
    for (int t = tid; t < nev; t += 1024) lm = lm > slev[t] ? lm : (int)slev[t];
    atomicMax(&smax, lm);
    __syncthreads();
    int nlev = smax + 1;

    // histogram
    for (int l = tid; l <= nev; l += 1024) scnt[l] = 0;
    __syncthreads();
    for (int t = tid; t < nev; t += 1024) atomicAdd(&scnt[slev[t]], 1);
    __syncthreads();

    // exclusive prefix (nlev is tiny, single thread)
    if (tid == 0) {
        int acc = 0;
        for (int l = 0; l < nlev; ++l) { int c = scnt[l]; scnt[l] = acc; acc += c; }
        scnt[nlev] = acc;
        *nlev_out = nlev;
    }
    __syncthreads();

    // write offsets to global
    for (int l = tid; l <= nlev; l += 1024) offs[l] = scnt[l];
    __syncthreads();

    // scatter (scnt doubles as cursors)
    for (int t = tid; t < nev; t += 1024) {
        int pos = atomicAdd(&scnt[slev[t]], 1);
        order[pos] = t;
    }
}

// ---------------------------------------------------------------------------
// Kernel 3 (cooperative): process levels with grid.sync() between them.
// One 256-thread block per event. GRU outputs go to per-event NU/NV buffers;
// an event reads either the pristine table row or NU/NV[prev] (indirection),
// so the input tables are never mutated.
// ---------------------------------------------------------------------------
__global__ __launch_bounds__(256, 2) void proc_kernel(
    const float* __restrict__ U0,  const float* __restrict__ V0,
    const float* __restrict__ Wui, const float* __restrict__ Wuh,
    const float* __restrict__ bui, const float* __restrict__ buh,
    const float* __restrict__ Wii, const float* __restrict__ Wih,
    const float* __restrict__ bii, const float* __restrict__ bih,
    const float* __restrict__ T1w, const float* __restrict__ T1b,
    const float* __restrict__ T2w, const float* __restrict__ T2b,
    const float* __restrict__ T3w, const float* __restrict__ T3b,
    const int* __restrict__ uids,  const int* __restrict__ iids,
    const int* __restrict__ prevu, const int* __restrict__ previ,
    const int* __restrict__ order, const int* __restrict__ offs,
    const int* __restrict__ nlev_p,
    float* __restrict__ NU, float* __restrict__ NV,
    float* __restrict__ out)
{
    cg::grid_group grid = cg::this_grid();

    __shared__ __align__(16) float su[EMB];
    __shared__ __align__(16) float sv[EMB];
    __shared__ __align__(16) float gg[1536];
    __shared__ __align__(16) float sh1[EMB];
    __shared__ __align__(16) float sh2[32];

    int tid = threadIdx.x;
    int nlev = *nlev_p;

    for (int l = 0; l < nlev; ++l) {
        int beg = offs[l], end = offs[l + 1];
        for (int k = beg + blockIdx.x; k < end; k += gridDim.x) {
            int t = order[k];
            int u_id = uids[t], i_id = iids[t];
            int pu = prevu[t], pi = previ[t];
            const float* up = (pu < 0) ? (U0 + (size_t)u_id * EMB) : (NU + (size_t)pu * EMB);
            const float* vp = (pi < 0) ? (V0 + (size_t)i_id * EMB) : (NV + (size_t)pi * EMB);

            if (tid < EMB) su[tid] = up[tid];
            else           sv[tid - EMB] = vp[tid - EMB];
            __syncthreads();

            // ---- base compatibility loss (wave 0) ----
            if (tid < 64) {
                float p = su[tid] * sv[tid] + su[tid + 64] * sv[tid + 64];
                for (int off = 32; off; off >>= 1) p += __shfl_xor(p, off);
                if (tid == 0) {
                    float sp = (p > 0.f) ? (p + log1pf(expf(-p))) : log1pf(expf(p));
                    out[2 * (size_t)t] = -logf(sp + 1e-10f);
                }
            }

            // ---- 1536 gate dots (6 per thread), length-128, fp32 ----
            #pragma unroll 1
            for (int q = 0; q < 6; ++q) {
                int o = tid + q * 256;           // 0..1535
                int grp = o / 384;               // wave-uniform
                int r = o - grp * 384;
                const float *W, *x, *b;
                if (grp == 0)      { W = Wui; x = sv; b = bui; }  // gi_user = Wui @ v
                else if (grp == 1) { W = Wuh; x = su; b = buh; }  // gh_user = Wuh @ u
                else if (grp == 2) { W = Wii; x = su; b = bii; }  // gi_item = Wii @ u
                else               { W = Wih; x = sv; b = bih; }  // gh_item = Wih @ v
                const float4* w4 = (const float4*)(W + (size_t)r * EMB);
                const float4* x4 = (const float4*)x;
                float a0 = 0.f, a1 = 0.f, a2 = 0.f, a3 = 0.f;
                #pragma unroll
                for (int kk = 0; kk < EMB / 4; ++kk) {
                    float4 w = w4[kk]; float4 xx = x4[kk];
                    a0 = fmaf(w.x, xx.x, a0);
                    a1 = fmaf(w.y, xx.y, a1);
                    a2 = fmaf(w.z, xx.z, a2);
                    a3 = fmaf(w.w, xx.w, a3);
                }
                gg[o] = (a0 + a1) + (a2 + a3) + b[r];
            }
            __syncthreads();

            // ---- GRU gate combine + scatter to NU/NV ----
            if (tid < EMB) {
                int e = tid;
                float r = sigmoidf_(gg[e]       + gg[384 + e]);
                float z = sigmoidf_(gg[128 + e] + gg[512 + e]);
                float n = tanhf(gg[256 + e] + r * gg[640 + e]);
                NU[(size_t)t * EMB + e] = (1.f - z) * n + z * su[e];
            } else {
                int e = tid - EMB;
                float r = sigmoidf_(gg[768 + e]  + gg[1152 + e]);
                float z = sigmoidf_(gg[896 + e]  + gg[1280 + e]);
                float n = tanhf(gg[1024 + e] + r * gg[1408 + e]);
                NV[(size_t)t * EMB + e] = (1.f - z) * n + z * sv[e];
            }

            // ---- MLP branch score (uses pre-update u,v) ----
            if (tid < EMB) {
                const float4* w4 = (const float4*)(T1w + (size_t)tid * 256);
                const float4* xu = (const float4*)su;
                const float4* xv = (const float4*)sv;
                float a0 = 0.f, a1 = 0.f, a2 = 0.f, a3 = 0.f;
                #pragma unroll
                for (int kk = 0; kk < EMB / 4; ++kk) {
                    float4 w = w4[kk]; float4 xx = xu[kk];
                    a0 = fmaf(w.x, xx.x, a0); a1 = fmaf(w.y, xx.y, a1);
                    a2 = fmaf(w.z, xx.z, a2); a3 = fmaf(w.w, xx.w, a3);
                }
                #pragma unroll
                for (int kk = 0; kk < EMB / 4; ++kk) {
                    float4 w = w4[32 + kk]; float4 xx = xv[kk];
                    a0 = fmaf(w.x, xx.x, a0); a1 = fmaf(w.y, xx.y, a1);
                    a2 = fmaf(w.z, xx.z, a2); a3 = fmaf(w.w, xx.w, a3);
                }
                float h = (a0 + a1) + (a2 + a3) + T1b[tid];
                sh1[tid] = h > 0.f ? h : 0.f;
            }
            __syncthreads();
            if (tid < 32) {
                const float4* w4 = (const float4*)(T2w + (size_t)tid * EMB);
                const float4* xh = (const float4*)sh1;
                float a0 = 0.f, a1 = 0.f, a2 = 0.f, a3 = 0.f;
                #pragma unroll
                for (int kk = 0; kk < EMB / 4; ++kk) {
                    float4 w = w4[kk]; float4 xx = xh[kk];
                    a0 = fmaf(w.x, xx.x, a0); a1 = fmaf(w.y, xx.y, a1);
                    a2 = fmaf(w.z, xx.z, a2); a3 = fmaf(w.w, xx.w, a3);
                }
                float h = (a0 + a1) + (a2 + a3) + T2b[tid];
                sh2[tid] = h > 0.f ? h : 0.f;
            }
            __syncthreads();
            if (tid < 32) {
                float p = T3w[tid] * sh2[tid];
                for (int off = 16; off; off >>= 1) p += __shfl_xor(p, off, 32);
                if (tid == 0) out[2 * (size_t)t + 1] = sigmoidf_(p + T3b[0]);
            }
            __syncthreads();  // protect su/sv/gg before next event
        }
        __threadfence();
        grid.sync();
    }
}

// ---------------------------------------------------------------------------
extern "C" void kernel_launch(void* const* d_in, const int* in_sizes, int n_in,
                              void* d_out, int out_size, void* d_ws, size_t ws_size,
                              hipStream_t stream)
{
    const float* U0  = (const float*)d_in[0];
    const float* V0  = (const float*)d_in[1];
    const float* Wui = (const float*)d_in[2];
    const float* Wuh = (const float*)d_in[3];
    const float* bui = (const float*)d_in[4];
    const float* buh = (const float*)d_in[5];
    const float* Wii = (const float*)d_in[6];
    const float* Wih = (const float*)d_in[7];
    const float* bii = (const float*)d_in[8];
    const float* bih = (const float*)d_in[9];
    const float* T1w = (const float*)d_in[10];
    const float* T1b = (const float*)d_in[11];
    const float* T2w = (const float*)d_in[12];
    const float* T2b = (const float*)d_in[13];
    const float* T3w = (const float*)d_in[14];
    const float* T3b = (const float*)d_in[15];
    const int* uids  = (const int*)d_in[16];
    const int* iids  = (const int*)d_in[17];
    int nev = in_sizes[16];

    char* ws = (char*)d_ws;
    int* prevu = (int*)ws;                      // MAXEV ints
    int* previ = prevu + MAXEV;                 // MAXEV ints
    int* order = previ + MAXEV;                 // MAXEV ints
    int* offs  = order + MAXEV;                 // MAXEV+2 ints
    int* nlevp = offs + MAXEV + 2;
    float* NU = (float*)(ws + (128 << 10));     // MAXEV*EMB floats (2MB)
    float* NV = NU + (size_t)MAXEV * EMB;       // 2MB
    float* out = (float*)d_out;

    prev_kernel<<<nev, 64, 0, stream>>>(uids, iids, prevu, previ, nev);
    level_kernel<<<1, 1024, 0, stream>>>(prevu, previ, order, offs, nlevp, nev);

    // cooperative grid sizing: exactly co-resident
    int nb = 2;
    (void)hipOccupancyMaxActiveBlocksPerMultiprocessor(&nb, proc_kernel, 256, 0);
    if (nb < 1) nb = 1;
    int ncu = 256;
    (void)hipDeviceGetAttribute(&ncu, hipDeviceAttributeMultiprocessorCount, 0);
    int grid = nb * ncu;
    if (grid > nev) grid = nev;
    if (grid < 1) grid = 1;

    void* args[] = {
        (void*)&U0, (void*)&V0,
        (void*)&Wui, (void*)&Wuh, (void*)&bui, (void*)&buh,
        (void*)&Wii, (void*)&Wih, (void*)&bii, (void*)&bih,
        (void*)&T1w, (void*)&T1b, (void*)&T2w, (void*)&T2b,
        (void*)&T3w, (void*)&T3b,
        (void*)&uids, (void*)&iids,
        (void*)&prevu, (void*)&previ,
        (void*)&order, (void*)&offs, (void*)&nlevp,
        (void*)&NU, (void*)&NV, (void*)&out
    };
    hipLaunchCooperativeKernel((void*)proc_kernel, dim3(grid), dim3(256),
                               args, 0, stream);
}

// Round 2
// 492.858 us; speedup vs baseline: 1.3670x; 1.3670x over previous
//
#include <hip/hip_runtime.h>
#include <hip/hip_cooperative_groups.h>
#include <math.h>

namespace cg = cooperative_groups;

#define EMB 128
#define PADW 132            // padded LDS row stride (floats): 16B-aligned, rotates banks
#define MAXEV 4096
#define EB 16               // events per GEMM group
#define GEMM_THRESH 1024    // level size above which the GEMM path wins

__device__ __forceinline__ float sigmoidf_(float x) { return 1.0f / (1.0f + expf(-x)); }
__device__ __forceinline__ float softplusf_(float x) {
    return (x > 0.f) ? x + log1pf(expf(-x)) : log1pf(expf(x));
}

// ---------------------------------------------------------------------------
// Kernel 1: most recent earlier event with same user / item id.
// ---------------------------------------------------------------------------
__global__ __launch_bounds__(64) void prev_kernel(
    const int* __restrict__ uids, const int* __restrict__ iids,
    int* __restrict__ prevu, int* __restrict__ previ, int nev)
{
    int t = blockIdx.x;
    if (t >= nev) return;
    int lane = threadIdx.x;
    int myu = uids[t], myi = iids[t];
    int bu = -1, bi = -1;
    for (int j = lane; j < t; j += 64) {
        if (uids[j] == myu) bu = j;
        if (iids[j] == myi) bi = j;
    }
    for (int off = 32; off; off >>= 1) {
        bu = max(bu, __shfl_xor(bu, off));
        bi = max(bi, __shfl_xor(bi, off));
    }
    if (lane == 0) { prevu[t] = bu; previ[t] = bi; }
}

// ---------------------------------------------------------------------------
// Kernel 2 (single block): DAG levels + counting sort by level.
// ---------------------------------------------------------------------------
__global__ __launch_bounds__(1024) void level_kernel(
    const int* __restrict__ prevu, const int* __restrict__ previ,
    int* __restrict__ order, int* __restrict__ offs,
    int* __restrict__ nlev_out, int nev)
{
    __shared__ int   spu[MAXEV];
    __shared__ int   spi[MAXEV];
    __shared__ short slev[MAXEV];
    __shared__ int   scnt[MAXEV + 1];
    __shared__ int   schanged;
    __shared__ int   smax;

    int tid = threadIdx.x;
    for (int t = tid; t < nev; t += 1024) {
        spu[t] = prevu[t];
        spi[t] = previ[t];
        slev[t] = 0;
    }
    __syncthreads();

    for (int it = 0; it < nev; ++it) {
        if (tid == 0) schanged = 0;
        __syncthreads();
        for (int t = tid; t < nev; t += 1024) {
            int pu = spu[t], pi = spi[t];
            int nl = 0;
            if (pu >= 0) nl = slev[pu] + 1;
            if (pi >= 0) { int c = slev[pi] + 1; nl = nl > c ? nl : c; }
            if (nl > (int)slev[t]) { slev[t] = (short)nl; schanged = 1; }
        }
        __syncthreads();
        if (!schanged) break;
    }

    if (tid == 0) smax = 0;
    __syncthreads();
    int lm = 0;
    for (int t = tid; t < nev; t += 1024) lm = lm > slev[t] ? lm : (int)slev[t];
    atomicMax(&smax, lm);
    __syncthreads();
    int nlev = smax + 1;

    for (int l = tid; l <= nev; l += 1024) scnt[l] = 0;
    __syncthreads();
    for (int t = tid; t < nev; t += 1024) atomicAdd(&scnt[slev[t]], 1);
    __syncthreads();

    if (tid == 0) {
        int acc = 0;
        for (int l = 0; l < nlev; ++l) { int c = scnt[l]; scnt[l] = acc; acc += c; }
        scnt[nlev] = acc;
        *nlev_out = nlev;
    }
    __syncthreads();
    for (int l = tid; l <= nlev; l += 1024) offs[l] = scnt[l];
    __syncthreads();
    for (int t = tid; t < nev; t += 1024) {
        int pos = atomicAdd(&scnt[slev[t]], 1);
        order[pos] = t;
    }
}

// ---------------------------------------------------------------------------
// GEMM piece: acc[e] += sum_k W[row][k] * x[ev][k] for a 64-row x 16-event
// tile, K=128. W staged global->LDS coalesced. Thread: row = tid>>2 (0..63),
// evq = tid&3 handles events evq*4..evq*4+3 (acc.x..acc.w).
// noinline: called 24+ times; keep I-footprint small. acc by value (VGPRs).
// ---------------------------------------------------------------------------
static __device__ __attribute__((noinline)) float4 gemm_piece(
    const float* __restrict__ Wbase, int strideF4,
    const float (*__restrict__ x)[PADW],
    float (*__restrict__ wt)[PADW],
    int tid, float4 acc)
{
    __syncthreads();                          // protect wt from prior readers
    const float4* src = (const float4*)Wbase;
    #pragma unroll
    for (int i = 0; i < 8; ++i) {
        int q = i * 256 + tid;                // 2048 float4 = 64x128 floats
        int r = q >> 5, c = (q & 31) << 2;
        float4 w = src[(size_t)r * strideF4 + (q & 31)];
        *(float4*)&wt[r][c] = w;
    }
    __syncthreads();
    int row = tid >> 2, evq = tid & 3;
    const float4* wr = (const float4*)&wt[row][0];
    const float4* x0 = (const float4*)&x[evq * 4 + 0][0];
    const float4* x1 = (const float4*)&x[evq * 4 + 1][0];
    const float4* x2 = (const float4*)&x[evq * 4 + 2][0];
    const float4* x3 = (const float4*)&x[evq * 4 + 3][0];
    #pragma unroll
    for (int k = 0; k < EMB / 4; ++k) {
        float4 w = wr[k];
        float4 a = x0[k];
        acc.x = fmaf(w.x, a.x, acc.x); acc.x = fmaf(w.y, a.y, acc.x);
        acc.x = fmaf(w.z, a.z, acc.x); acc.x = fmaf(w.w, a.w, acc.x);
        float4 b = x1[k];
        acc.y = fmaf(w.x, b.x, acc.y); acc.y = fmaf(w.y, b.y, acc.y);
        acc.y = fmaf(w.z, b.z, acc.y); acc.y = fmaf(w.w, b.w, acc.y);
        float4 c = x2[k];
        acc.z = fmaf(w.x, c.x, acc.z); acc.z = fmaf(w.y, c.y, acc.z);
        acc.z = fmaf(w.z, c.z, acc.z); acc.z = fmaf(w.w, c.w, acc.z);
        float4 d = x3[k];
        acc.w = fmaf(w.x, d.x, acc.w); acc.w = fmaf(w.y, d.y, acc.w);
        acc.w = fmaf(w.z, d.z, acc.w); acc.w = fmaf(w.w, d.w, acc.w);
    }
    return acc;
}

struct ProcSmem {
    float xu[EB][PADW];
    float xv[EB][PADW];
    float wt[64][PADW];
    int   s_t[EB];
};
struct EvSmem {
    float xi[EMB];
    float xh[EMB];
    float d[2][3][64];
};

// ---------------------------------------------------------------------------
// Kernel 3 (cooperative): per-level GRU updates. Big levels: 16-event GEMM
// groups. Small levels: 4 blocks/event (gru x half), 16 lanes per row.
// ---------------------------------------------------------------------------
__global__ __launch_bounds__(256) void proc_kernel(
    const float* __restrict__ U0,  const float* __restrict__ V0,
    const float* __restrict__ Wui, const float* __restrict__ Wuh,
    const float* __restrict__ bui, const float* __restrict__ buh,
    const float* __restrict__ Wii, const float* __restrict__ Wih,
    const float* __restrict__ bii, const float* __restrict__ bih,
    const int* __restrict__ uids,  const int* __restrict__ iids,
    const int* __restrict__ prevu, const int* __restrict__ previ,
    const int* __restrict__ order, const int* __restrict__ offs,
    const int* __restrict__ nlev_p,
    float* __restrict__ NU, float* __restrict__ NV)
{
    cg::grid_group grid = cg::this_grid();
    __shared__ __align__(16) char smraw[sizeof(ProcSmem)];

    int tid = threadIdx.x;
    int nlev = *nlev_p;

    for (int l = 0; l < nlev; ++l) {
        int beg = offs[l], end = offs[l + 1];
        int cnt = end - beg;

        if (cnt > GEMM_THRESH) {
            // ---------------- GEMM path ----------------
            ProcSmem* sm = (ProcSmem*)smraw;
            int ngrp = (cnt + EB - 1) / EB;
            for (int g = blockIdx.x; g < ngrp; g += gridDim.x) {
                __syncthreads();
                if (tid < EB) {
                    int kk = beg + g * EB + tid;
                    sm->s_t[tid] = (kk < end) ? order[kk] : -1;
                }
                __syncthreads();
                {   // gather u,v (16 lanes x 8 floats per event)
                    int ev = tid >> 4, j = tid & 15;
                    int t = sm->s_t[ev];
                    if (t >= 0) {
                        int pu = prevu[t], pi = previ[t];
                        const float4* up = (const float4*)(pu < 0 ?
                            U0 + (size_t)uids[t] * EMB : NU + (size_t)pu * EMB);
                        const float4* vp = (const float4*)(pi < 0 ?
                            V0 + (size_t)iids[t] * EMB : NV + (size_t)pi * EMB);
                        float4 a = up[2 * j], b = up[2 * j + 1];
                        *(float4*)&sm->xu[ev][8 * j]     = a;
                        *(float4*)&sm->xu[ev][8 * j + 4] = b;
                        float4 c = vp[2 * j], d = vp[2 * j + 1];
                        *(float4*)&sm->xv[ev][8 * j]     = c;
                        *(float4*)&sm->xv[ev][8 * j + 4] = d;
                    }
                }
                // (gemm_piece starts with __syncthreads -> gather visible)
                int row = tid >> 2, evq = tid & 3;
                #pragma unroll 1
                for (int gm = 0; gm < 4; ++gm) {
                    int gru = gm >> 1, m = gm & 1;
                    const float* Wi = gru ? Wii : Wui;
                    const float* Wh = gru ? Wih : Wuh;
                    const float* bi = gru ? bii : bui;
                    const float* bh = gru ? bih : buh;
                    const float (*xi)[PADW] = gru ? sm->xu : sm->xv;
                    const float (*xh)[PADW] = gru ? sm->xv : sm->xu;
                    float* Nout = gru ? NV : NU;
                    int rbase = m * 64;

                    float b1 = bi[128 + rbase + row] + bh[128 + rbase + row];
                    float4 zz = make_float4(b1, b1, b1, b1);
                    zz = gemm_piece(Wi + (size_t)(128 + rbase) * EMB, 32, xi, sm->wt, tid, zz);
                    zz = gemm_piece(Wh + (size_t)(128 + rbase) * EMB, 32, xh, sm->wt, tid, zz);

                    float b2 = bi[rbase + row] + bh[rbase + row];
                    float4 rr = make_float4(b2, b2, b2, b2);
                    rr = gemm_piece(Wi + (size_t)rbase * EMB, 32, xi, sm->wt, tid, rr);
                    rr = gemm_piece(Wh + (size_t)rbase * EMB, 32, xh, sm->wt, tid, rr);

                    float b3 = bi[256 + rbase + row];
                    float4 ni = make_float4(b3, b3, b3, b3);
                    ni = gemm_piece(Wi + (size_t)(256 + rbase) * EMB, 32, xi, sm->wt, tid, ni);

                    float b4 = bh[256 + rbase + row];
                    float4 nh = make_float4(b4, b4, b4, b4);
                    nh = gemm_piece(Wh + (size_t)(256 + rbase) * EMB, 32, xh, sm->wt, tid, nh);

                    #define COMB(E, ZV, RV, NIV, NHV) { \
                        int ev_ = evq * 4 + (E); int tt_ = sm->s_t[ev_]; \
                        if (tt_ >= 0) { \
                            float z_ = sigmoidf_(ZV), r_ = sigmoidf_(RV); \
                            float n_ = tanhf((NIV) + r_ * (NHV)); \
                            Nout[(size_t)tt_ * EMB + rbase + row] = \
                                (1.f - z_) * n_ + z_ * xh[ev_][rbase + row]; \
                        } }
                    COMB(0, zz.x, rr.x, ni.x, nh.x)
                    COMB(1, zz.y, rr.y, ni.y, nh.y)
                    COMB(2, zz.z, rr.z, ni.z, nh.z)
                    COMB(3, zz.w, rr.w, ni.w, nh.w)
                    #undef COMB
                }
            }
        } else {
            // ---------------- per-event path: 4 blocks per event ----------------
            EvSmem* sm = (EvSmem*)smraw;
            int ntask = cnt * 4;
            for (int task = blockIdx.x; task < ntask; task += gridDim.x) {
                int t = order[beg + (task >> 2)];
                int gru = (task >> 1) & 1, h = task & 1;
                int pu = prevu[t], pi = previ[t];
                const float* up = pu < 0 ? U0 + (size_t)uids[t] * EMB : NU + (size_t)pu * EMB;
                const float* vp = pi < 0 ? V0 + (size_t)iids[t] * EMB : NV + (size_t)pi * EMB;
                const float* xip = gru ? up : vp;   // gi input: user uses v, item uses u
                const float* xhp = gru ? vp : up;   // gh input = h_prev
                __syncthreads();
                if (tid < EMB) sm->xi[tid] = xip[tid];
                else           sm->xh[tid - EMB] = xhp[tid - EMB];
                __syncthreads();
                const float* Wi = gru ? Wii : Wui;
                const float* Wh = gru ? Wih : Wuh;
                int j = tid & 15, rg = tid >> 4;
                #pragma unroll 1
                for (int p = 0; p < 24; ++p) {
                    int mat = p / 12, gg = (p % 12) >> 2, pp = p & 3;
                    int e = pp * 16 + rg;                  // 0..63
                    int grow = gg * 128 + h * 64 + e;
                    const float* W = (mat ? Wh : Wi) + (size_t)grow * EMB;
                    const float* x = mat ? sm->xh : sm->xi;
                    float4 w0 = ((const float4*)W)[2 * j], w1 = ((const float4*)W)[2 * j + 1];
                    float4 xa = ((const float4*)x)[2 * j], xb = ((const float4*)x)[2 * j + 1];
                    float s;
                    s  = w0.x * xa.x; s = fmaf(w0.y, xa.y, s);
                    s = fmaf(w0.z, xa.z, s); s = fmaf(w0.w, xa.w, s);
                    s = fmaf(w1.x, xb.x, s); s = fmaf(w1.y, xb.y, s);
                    s = fmaf(w1.z, xb.z, s); s = fmaf(w1.w, xb.w, s);
                    s += __shfl_xor(s, 1); s += __shfl_xor(s, 2);
                    s += __shfl_xor(s, 4); s += __shfl_xor(s, 8);
                    if (j == 0) sm->d[mat][gg][e] = s;
                }
                __syncthreads();
                if (tid < 64) {
                    int e = tid;
                    const float* bi = gru ? bii : bui;
                    const float* bh = gru ? bih : buh;
                    int o = h * 64 + e;
                    float r = sigmoidf_(sm->d[0][0][e] + bi[o]       + sm->d[1][0][e] + bh[o]);
                    float z = sigmoidf_(sm->d[0][1][e] + bi[128 + o] + sm->d[1][1][e] + bh[128 + o]);
                    float n = tanhf(sm->d[0][2][e] + bi[256 + o] + r * (sm->d[1][2][e] + bh[256 + o]));
                    float hp = sm->xh[o];
                    float* N = gru ? NV : NU;
                    N[(size_t)t * EMB + o] = (1.f - z) * n + z * hp;
                }
            }
        }
        __threadfence();
        grid.sync();
    }
}

struct PostSmem {
    float xu[EB][PADW];
    float xv[EB][PADW];
    float wt[64][PADW];
    float h1[EB][PADW];
    float h2[EB][36];
    int   s_t[EB];
};

// ---------------------------------------------------------------------------
// Kernel 4: loss + MLP branch for all events (depends only on event inputs).
// ---------------------------------------------------------------------------
__global__ __launch_bounds__(256) void post_kernel(
    const float* __restrict__ U0,  const float* __restrict__ V0,
    const float* __restrict__ T1w, const float* __restrict__ T1b,
    const float* __restrict__ T2w, const float* __restrict__ T2b,
    const float* __restrict__ T3w, const float* __restrict__ T3b,
    const int* __restrict__ uids,  const int* __restrict__ iids,
    const int* __restrict__ prevu, const int* __restrict__ previ,
    const float* __restrict__ NU,  const float* __restrict__ NV,
    float* __restrict__ out, int nev)
{
    __shared__ __align__(16) PostSmem sm;
    int tid = threadIdx.x;
    int base = blockIdx.x * EB;

    if (tid < EB) sm.s_t[tid] = (base + tid < nev) ? base + tid : -1;
    __syncthreads();

    {   // gather + loss
        int ev = tid >> 4, j = tid & 15;
        int t = sm.s_t[ev];
        float4 a = make_float4(0, 0, 0, 0), b = a, c = a, d = a;
        if (t >= 0) {
            int pu = prevu[t], pi = previ[t];
            const float4* up = (const float4*)(pu < 0 ?
                U0 + (size_t)uids[t] * EMB : NU + (size_t)pu * EMB);
            const float4* vp = (const float4*)(pi < 0 ?
                V0 + (size_t)iids[t] * EMB : NV + (size_t)pi * EMB);
            a = up[2 * j]; b = up[2 * j + 1];
            c = vp[2 * j]; d = vp[2 * j + 1];
            *(float4*)&sm.xu[ev][8 * j]     = a;
            *(float4*)&sm.xu[ev][8 * j + 4] = b;
            *(float4*)&sm.xv[ev][8 * j]     = c;
            *(float4*)&sm.xv[ev][8 * j + 4] = d;
        }
        float dp = a.x * c.x + a.y * c.y + a.z * c.z + a.w * c.w
                 + b.x * d.x + b.y * d.y + b.z * d.z + b.w * d.w;
        dp += __shfl_xor(dp, 1); dp += __shfl_xor(dp, 2);
        dp += __shfl_xor(dp, 4); dp += __shfl_xor(dp, 8);
        if (j == 0 && t >= 0)
            out[2 * (size_t)t] = -logf(softplusf_(dp) + 1e-10f);
    }

    // T1: h1 = relu(T1w @ [u;v] + b)   (128 rows, K=256 as two K=128 pieces)
    int row = tid >> 2, evq = tid & 3;
    #pragma unroll 1
    for (int m = 0; m < 2; ++m) {
        float bb = T1b[m * 64 + row];
        float4 a4 = make_float4(bb, bb, bb, bb);
        a4 = gemm_piece(T1w + (size_t)(m * 64) * 256,       64, sm.xu, sm.wt, tid, a4);
        a4 = gemm_piece(T1w + (size_t)(m * 64) * 256 + 128, 64, sm.xv, sm.wt, tid, a4);
        sm.h1[evq * 4 + 0][m * 64 + row] = fmaxf(a4.x, 0.f);
        sm.h1[evq * 4 + 1][m * 64 + row] = fmaxf(a4.y, 0.f);
        sm.h1[evq * 4 + 2][m * 64 + row] = fmaxf(a4.z, 0.f);
        sm.h1[evq * 4 + 3][m * 64 + row] = fmaxf(a4.w, 0.f);
    }
    __syncthreads();

    // T2: h2 = relu(T2w @ h1 + b)   (32 rows)
    {
        const float4* s2 = (const float4*)T2w;
        #pragma unroll
        for (int i = 0; i < 4; ++i) {
            int q = i * 256 + tid;            // 1024 float4 = 32x128
            int r = q >> 5, c = (q & 31) << 2;
            float4 w = s2[q];
            *(float4*)&sm.wt[r][c] = w;
        }
        __syncthreads();
        int r2 = tid >> 3, evp = tid & 7;
        float acc0 = T2b[r2], acc1 = T2b[r2];
        const float4* wr = (const float4*)&sm.wt[r2][0];
        const float4* xa = (const float4*)&sm.h1[evp][0];
        const float4* xb = (const float4*)&sm.h1[evp + 8][0];
        #pragma unroll
        for (int k = 0; k < 32; ++k) {
            float4 w = wr[k], p = xa[k], q4 = xb[k];
            acc0 = fmaf(w.x, p.x, acc0);  acc0 = fmaf(w.y, p.y, acc0);
            acc0 = fmaf(w.z, p.z, acc0);  acc0 = fmaf(w.w, p.w, acc0);
            acc1 = fmaf(w.x, q4.x, acc1); acc1 = fmaf(w.y, q4.y, acc1);
            acc1 = fmaf(w.z, q4.z, acc1); acc1 = fmaf(w.w, q4.w, acc1);
        }
        sm.h2[evp][r2]     = fmaxf(acc0, 0.f);
        sm.h2[evp + 8][r2] = fmaxf(acc1, 0.f);
        __syncthreads();
    }

    // T3 + sigmoid
    {
        int ev = tid >> 4, j = tid & 15;
        float p = T3w[2 * j] * sm.h2[ev][2 * j] + T3w[2 * j + 1] * sm.h2[ev][2 * j + 1];
        p += __shfl_xor(p, 1); p += __shfl_xor(p, 2);
        p += __shfl_xor(p, 4); p += __shfl_xor(p, 8);
        int t = sm.s_t[ev];
        if (j == 0 && t >= 0)
            out[2 * (size_t)t + 1] = sigmoidf_(p + T3b[0]);
    }
}

// ---------------------------------------------------------------------------
extern "C" void kernel_launch(void* const* d_in, const int* in_sizes, int n_in,
                              void* d_out, int out_size, void* d_ws, size_t ws_size,
                              hipStream_t stream)
{
    const float* U0  = (const float*)d_in[0];
    const float* V0  = (const float*)d_in[1];
    const float* Wui = (const float*)d_in[2];
    const float* Wuh = (const float*)d_in[3];
    const float* bui = (const float*)d_in[4];
    const float* buh = (const float*)d_in[5];
    const float* Wii = (const float*)d_in[6];
    const float* Wih = (const float*)d_in[7];
    const float* bii = (const float*)d_in[8];
    const float* bih = (const float*)d_in[9];
    const float* T1w = (const float*)d_in[10];
    const float* T1b = (const float*)d_in[11];
    const float* T2w = (const float*)d_in[12];
    const float* T2b = (const float*)d_in[13];
    const float* T3w = (const float*)d_in[14];
    const float* T3b = (const float*)d_in[15];
    const int* uids  = (const int*)d_in[16];
    const int* iids  = (const int*)d_in[17];
    int nev = in_sizes[16];

    char* ws = (char*)d_ws;
    int* prevu = (int*)ws;
    int* previ = prevu + MAXEV;
    int* order = previ + MAXEV;
    int* offs  = order + MAXEV;
    int* nlevp = offs + MAXEV + 2;
    float* NU = (float*)(ws + (128 << 10));
    float* NV = NU + (size_t)MAXEV * EMB;
    float* out = (float*)d_out;

    prev_kernel<<<nev, 64, 0, stream>>>(uids, iids, prevu, previ, nev);
    level_kernel<<<1, 1024, 0, stream>>>(prevu, previ, order, offs, nlevp, nev);

    int nb = 1;
    (void)hipOccupancyMaxActiveBlocksPerMultiprocessor(&nb, proc_kernel, 256, 0);
    if (nb < 1) nb = 1;
    int ncu = 256;
    (void)hipDeviceGetAttribute(&ncu, hipDeviceAttributeMultiprocessorCount, 0);
    int grid = nb * ncu;
    if (grid > 1024) grid = 1024;

    void* args[] = {
        (void*)&U0, (void*)&V0,
        (void*)&Wui, (void*)&Wuh, (void*)&bui, (void*)&buh,
        (void*)&Wii, (void*)&Wih, (void*)&bii, (void*)&bih,
        (void*)&uids, (void*)&iids,
        (void*)&prevu, (void*)&previ,
        (void*)&order, (void*)&offs, (void*)&nlevp,
        (void*)&NU, (void*)&NV
    };
    hipLaunchCooperativeKernel((void*)proc_kernel, dim3(grid), dim3(256),
                               args, 0, stream);

    int pblocks = (nev + EB - 1) / EB;
    post_kernel<<<pblocks, 256, 0, stream>>>(
        U0, V0, T1w, T1b, T2w, T2b, T3w, T3b,
        uids, iids, prevu, previ, NU, NV, out, nev);
}

// Round 3
// 273.076 us; speedup vs baseline: 2.4672x; 1.8048x over previous
//
#include <hip/hip_runtime.h>
#include <math.h>

#define EMB 128
#define PADW 132            // padded LDS row stride (floats)
#define MAXEV 4096
#define EB 16               // events per GEMM group

struct Hdr { int nl0; int ncomp; };

__device__ __forceinline__ float sigmoidf_(float x) { return 1.0f / (1.0f + expf(-x)); }
__device__ __forceinline__ float softplusf_(float x) {
    return (x > 0.f) ? x + log1pf(expf(-x)) : log1pf(expf(x));
}

// ---------------------------------------------------------------------------
// Kernel 1: most recent earlier event with same user / item id.
// ---------------------------------------------------------------------------
__global__ __launch_bounds__(64) void prev_kernel(
    const int* __restrict__ uids, const int* __restrict__ iids,
    int* __restrict__ prevu, int* __restrict__ previ, int nev)
{
    int t = blockIdx.x;
    if (t >= nev) return;
    int lane = threadIdx.x;
    int myu = uids[t], myi = iids[t];
    int bu = -1, bi = -1;
    for (int j = lane; j < t; j += 64) {
        if (uids[j] == myu) bu = j;
        if (iids[j] == myi) bi = j;
    }
    for (int off = 32; off; off >>= 1) {
        bu = max(bu, __shfl_xor(bu, off));
        bi = max(bi, __shfl_xor(bi, off));
    }
    if (lane == 0) { prevu[t] = bu; previ[t] = bi; }
}

// ---------------------------------------------------------------------------
// Kernel 2 (single block): connected components over prev edges (min-label
// propagation), partition into level-0 (no preds) vs tail, sort tail by
// (component, t), emit component start offsets.
// ---------------------------------------------------------------------------
__global__ __launch_bounds__(1024) void setup_kernel(
    const int* __restrict__ prevu, const int* __restrict__ previ,
    int* __restrict__ l0order, int* __restrict__ tailOrder,
    int* __restrict__ compStart, Hdr* __restrict__ hdr, int nev)
{
    __shared__ int lab[MAXEV];
    __shared__ int tmpT[MAXEV];
    __shared__ int skey[MAXEV];
    __shared__ int schanged, sntail, snl0;

    int tid = threadIdx.x;
    for (int t = tid; t < nev; t += 1024) lab[t] = t;
    if (tid == 0) { sntail = 0; snl0 = 0; }
    __syncthreads();

    // min-label propagation over undirected prev edges (converges in diameter)
    for (int it = 0; it < nev; ++it) {
        if (tid == 0) schanged = 0;
        __syncthreads();
        for (int t = tid; t < nev; t += 1024) {
            int m = lab[t];
            int pu = prevu[t], pi = previ[t];
            if (pu >= 0) m = min(m, lab[pu]);
            if (pi >= 0) m = min(m, lab[pi]);
            if (m < lab[t]) { atomicMin(&lab[t], m); schanged = 1; }
            if (pu >= 0 && m < lab[pu]) { atomicMin(&lab[pu], m); schanged = 1; }
            if (pi >= 0 && m < lab[pi]) { atomicMin(&lab[pi], m); schanged = 1; }
        }
        __syncthreads();
        if (!schanged) break;
        __syncthreads();
    }

    // partition: level-0 (no preds) vs tail
    for (int t = tid; t < nev; t += 1024) {
        if (prevu[t] >= 0 || previ[t] >= 0) {
            int i = atomicAdd(&sntail, 1);
            tmpT[i] = t;
        } else {
            int i = atomicAdd(&snl0, 1);
            l0order[i] = t;
        }
    }
    __syncthreads();
    int ntail = sntail;

    // key = (component label << 12) | t   (both < 4096)
    for (int i = tid; i < ntail; i += 1024)
        skey[i] = (lab[tmpT[i]] << 12) | tmpT[i];
    __syncthreads();

    // rank-sort (keys unique); store sorted keys into lab[] (reused)
    for (int i = tid; i < ntail; i += 1024) {
        int k = skey[i], r = 0;
        for (int j = 0; j < ntail; ++j) r += (skey[j] < k);
        tailOrder[r] = tmpT[i];
        lab[r] = k;
    }
    __syncthreads();

    if (tid == 0) {
        int nc = 0;
        for (int i = 0; i < ntail; ++i)
            if (i == 0 || (lab[i] >> 12) != (lab[i - 1] >> 12))
                compStart[nc++] = i;
        compStart[nc] = ntail;
        hdr->ncomp = nc;
        hdr->nl0 = snl0;
    }
}

// ---------------------------------------------------------------------------
// GEMM piece (unchanged from round 2): acc[e] += sum_k W[row][k]*x[ev][k]
// for a 64-row x 16-event tile, K=128.
// ---------------------------------------------------------------------------
static __device__ __attribute__((noinline)) float4 gemm_piece(
    const float* __restrict__ Wbase, int strideF4,
    const float (*__restrict__ x)[PADW],
    float (*__restrict__ wt)[PADW],
    int tid, float4 acc)
{
    __syncthreads();
    const float4* src = (const float4*)Wbase;
    #pragma unroll
    for (int i = 0; i < 8; ++i) {
        int q = i * 256 + tid;
        int r = q >> 5, c = (q & 31) << 2;
        float4 w = src[(size_t)r * strideF4 + (q & 31)];
        *(float4*)&wt[r][c] = w;
    }
    __syncthreads();
    int row = tid >> 2, evq = tid & 3;
    const float4* wr = (const float4*)&wt[row][0];
    const float4* x0 = (const float4*)&x[evq * 4 + 0][0];
    const float4* x1 = (const float4*)&x[evq * 4 + 1][0];
    const float4* x2 = (const float4*)&x[evq * 4 + 2][0];
    const float4* x3 = (const float4*)&x[evq * 4 + 3][0];
    #pragma unroll
    for (int k = 0; k < EMB / 4; ++k) {
        float4 w = wr[k];
        float4 a = x0[k];
        acc.x = fmaf(w.x, a.x, acc.x); acc.x = fmaf(w.y, a.y, acc.x);
        acc.x = fmaf(w.z, a.z, acc.x); acc.x = fmaf(w.w, a.w, acc.x);
        float4 b = x1[k];
        acc.y = fmaf(w.x, b.x, acc.y); acc.y = fmaf(w.y, b.y, acc.y);
        acc.y = fmaf(w.z, b.z, acc.y); acc.y = fmaf(w.w, b.w, acc.y);
        float4 c = x2[k];
        acc.z = fmaf(w.x, c.x, acc.z); acc.z = fmaf(w.y, c.y, acc.z);
        acc.z = fmaf(w.z, c.z, acc.z); acc.z = fmaf(w.w, c.w, acc.z);
        float4 d = x3[k];
        acc.w = fmaf(w.x, d.x, acc.w); acc.w = fmaf(w.y, d.y, acc.w);
        acc.w = fmaf(w.z, d.z, acc.w); acc.w = fmaf(w.w, d.w, acc.w);
    }
    return acc;
}

struct ProcSmem {
    float xu[EB][PADW];
    float xv[EB][PADW];
    float wt[64][PADW];
    int   s_t[EB];
};

// ---------------------------------------------------------------------------
// Kernel 3: all no-predecessor events via 16-event GEMM groups. No grid sync.
// ---------------------------------------------------------------------------
__global__ __launch_bounds__(256) void gemm_l0_kernel(
    const float* __restrict__ U0,  const float* __restrict__ V0,
    const float* __restrict__ Wui, const float* __restrict__ Wuh,
    const float* __restrict__ bui, const float* __restrict__ buh,
    const float* __restrict__ Wii, const float* __restrict__ Wih,
    const float* __restrict__ bii, const float* __restrict__ bih,
    const int* __restrict__ uids,  const int* __restrict__ iids,
    const int* __restrict__ l0order, const Hdr* __restrict__ hdr,
    float* __restrict__ NU, float* __restrict__ NV)
{
    __shared__ __align__(16) ProcSmem sm;
    int tid = threadIdx.x;
    int nl0 = hdr->nl0;
    int ngrp = (nl0 + EB - 1) / EB;

    for (int g = blockIdx.x; g < ngrp; g += gridDim.x) {
        __syncthreads();
        if (tid < EB) {
            int kk = g * EB + tid;
            sm.s_t[tid] = (kk < nl0) ? l0order[kk] : -1;
        }
        __syncthreads();
        {   // gather u,v (level-0 events have no preds -> read tables)
            int ev = tid >> 4, j = tid & 15;
            int t = sm.s_t[ev];
            if (t >= 0) {
                const float4* up = (const float4*)(U0 + (size_t)uids[t] * EMB);
                const float4* vp = (const float4*)(V0 + (size_t)iids[t] * EMB);
                float4 a = up[2 * j], b = up[2 * j + 1];
                *(float4*)&sm.xu[ev][8 * j]     = a;
                *(float4*)&sm.xu[ev][8 * j + 4] = b;
                float4 c = vp[2 * j], d = vp[2 * j + 1];
                *(float4*)&sm.xv[ev][8 * j]     = c;
                *(float4*)&sm.xv[ev][8 * j + 4] = d;
            }
        }
        int row = tid >> 2, evq = tid & 3;
        #pragma unroll 1
        for (int gm = 0; gm < 4; ++gm) {
            int gru = gm >> 1, m = gm & 1;
            const float* Wi = gru ? Wii : Wui;
            const float* Wh = gru ? Wih : Wuh;
            const float* bi = gru ? bii : bui;
            const float* bh = gru ? bih : buh;
            const float (*xi)[PADW] = gru ? sm.xu : sm.xv;
            const float (*xh)[PADW] = gru ? sm.xv : sm.xu;
            float* Nout = gru ? NV : NU;
            int rbase = m * 64;

            float b1 = bi[128 + rbase + row] + bh[128 + rbase + row];
            float4 zz = make_float4(b1, b1, b1, b1);
            zz = gemm_piece(Wi + (size_t)(128 + rbase) * EMB, 32, xi, sm.wt, tid, zz);
            zz = gemm_piece(Wh + (size_t)(128 + rbase) * EMB, 32, xh, sm.wt, tid, zz);

            float b2 = bi[rbase + row] + bh[rbase + row];
            float4 rr = make_float4(b2, b2, b2, b2);
            rr = gemm_piece(Wi + (size_t)rbase * EMB, 32, xi, sm.wt, tid, rr);
            rr = gemm_piece(Wh + (size_t)rbase * EMB, 32, xh, sm.wt, tid, rr);

            float b3 = bi[256 + rbase + row];
            float4 ni = make_float4(b3, b3, b3, b3);
            ni = gemm_piece(Wi + (size_t)(256 + rbase) * EMB, 32, xi, sm.wt, tid, ni);

            float b4 = bh[256 + rbase + row];
            float4 nh = make_float4(b4, b4, b4, b4);
            nh = gemm_piece(Wh + (size_t)(256 + rbase) * EMB, 32, xh, sm.wt, tid, nh);

            #define COMB(E, ZV, RV, NIV, NHV) { \
                int ev_ = evq * 4 + (E); int tt_ = sm.s_t[ev_]; \
                if (tt_ >= 0) { \
                    float z_ = sigmoidf_(ZV), r_ = sigmoidf_(RV); \
                    float n_ = tanhf((NIV) + r_ * (NHV)); \
                    Nout[(size_t)tt_ * EMB + rbase + row] = \
                        (1.f - z_) * n_ + z_ * xh[ev_][rbase + row]; \
                } }
            COMB(0, zz.x, rr.x, ni.x, nh.x)
            COMB(1, zz.y, rr.y, ni.y, nh.y)
            COMB(2, zz.z, rr.z, ni.z, nh.z)
            COMB(3, zz.w, rr.w, ni.w, nh.w)
            #undef COMB
        }
    }
}

struct TailSmem {
    float su[EMB];
    float sv[EMB];
    float gg[1536];
};

// ---------------------------------------------------------------------------
// Kernel 4: dependent events. One block per component; sequential in t within
// the component (all deps are component-internal). No inter-block comms.
// ---------------------------------------------------------------------------
__global__ __launch_bounds__(256) void tail_kernel(
    const float* __restrict__ U0,  const float* __restrict__ V0,
    const float* __restrict__ Wui, const float* __restrict__ Wuh,
    const float* __restrict__ bui, const float* __restrict__ buh,
    const float* __restrict__ Wii, const float* __restrict__ Wih,
    const float* __restrict__ bii, const float* __restrict__ bih,
    const int* __restrict__ uids,  const int* __restrict__ iids,
    const int* __restrict__ prevu, const int* __restrict__ previ,
    const int* __restrict__ tailOrder, const int* __restrict__ compStart,
    const Hdr* __restrict__ hdr,
    float* __restrict__ NU, float* __restrict__ NV)
{
    __shared__ __align__(16) TailSmem sm;
    int tid = threadIdx.x;
    int ncomp = hdr->ncomp;

    for (int c = blockIdx.x; c < ncomp; c += gridDim.x) {
        int kb = compStart[c], ke = compStart[c + 1];
        for (int k = kb; k < ke; ++k) {
            int t = tailOrder[k];
            int pu = prevu[t], pi = previ[t];
            const float* up = (pu < 0) ? U0 + (size_t)uids[t] * EMB : NU + (size_t)pu * EMB;
            const float* vp = (pi < 0) ? V0 + (size_t)iids[t] * EMB : NV + (size_t)pi * EMB;
            __syncthreads();   // protect sm reuse + make same-block NU/NV writes visible
            if (tid < EMB) sm.su[tid] = up[tid];
            else           sm.sv[tid - EMB] = vp[tid - EMB];
            __syncthreads();

            int g = tid >> 4, j = tid & 15;
            #pragma unroll 4
            for (int pp = 0; pp < 96; ++pp) {
                int rg = pp * 16 + g;            // 0..1535
                int mat = rg / 384;              // uniform within 16-lane group
                int r = rg - mat * 384;
                const float* W = (mat == 0) ? Wui : (mat == 1) ? Wuh : (mat == 2) ? Wii : Wih;
                const float* x = (mat == 1 || mat == 2) ? sm.su : sm.sv;
                const float4* W4 = (const float4*)(W + (size_t)r * EMB);
                const float4* x4 = (const float4*)x;
                float4 w0 = W4[2 * j], w1 = W4[2 * j + 1];
                float4 xa = x4[2 * j], xb = x4[2 * j + 1];
                float s;
                s  = w0.x * xa.x;        s = fmaf(w0.y, xa.y, s);
                s = fmaf(w0.z, xa.z, s); s = fmaf(w0.w, xa.w, s);
                s = fmaf(w1.x, xb.x, s); s = fmaf(w1.y, xb.y, s);
                s = fmaf(w1.z, xb.z, s); s = fmaf(w1.w, xb.w, s);
                s += __shfl_xor(s, 1); s += __shfl_xor(s, 2);
                s += __shfl_xor(s, 4); s += __shfl_xor(s, 8);
                if (j == 0) sm.gg[rg] = s;
            }
            __syncthreads();

            if (tid < EMB) {
                int e = tid;
                float r_ = sigmoidf_(sm.gg[e] + bui[e] + sm.gg[384 + e] + buh[e]);
                float z_ = sigmoidf_(sm.gg[128 + e] + bui[128 + e] + sm.gg[512 + e] + buh[128 + e]);
                float n_ = tanhf(sm.gg[256 + e] + bui[256 + e] + r_ * (sm.gg[640 + e] + buh[256 + e]));
                NU[(size_t)t * EMB + e] = (1.f - z_) * n_ + z_ * sm.su[e];
            } else {
                int e = tid - EMB;
                float r_ = sigmoidf_(sm.gg[768 + e] + bii[e] + sm.gg[1152 + e] + bih[e]);
                float z_ = sigmoidf_(sm.gg[896 + e] + bii[128 + e] + sm.gg[1280 + e] + bih[128 + e]);
                float n_ = tanhf(sm.gg[1024 + e] + bii[256 + e] + r_ * (sm.gg[1408 + e] + bih[256 + e]));
                NV[(size_t)t * EMB + e] = (1.f - z_) * n_ + z_ * sm.sv[e];
            }
        }
    }
}

struct PostSmem {
    float xu[EB][PADW];
    float xv[EB][PADW];
    float wt[64][PADW];
    float h1[EB][PADW];
    float h2[EB][36];
    int   s_t[EB];
};

// ---------------------------------------------------------------------------
// Kernel 5: loss + MLP branch for all events (reads event INPUT u,v).
// ---------------------------------------------------------------------------
__global__ __launch_bounds__(256) void post_kernel(
    const float* __restrict__ U0,  const float* __restrict__ V0,
    const float* __restrict__ T1w, const float* __restrict__ T1b,
    const float* __restrict__ T2w, const float* __restrict__ T2b,
    const float* __restrict__ T3w, const float* __restrict__ T3b,
    const int* __restrict__ uids,  const int* __restrict__ iids,
    const int* __restrict__ prevu, const int* __restrict__ previ,
    const float* __restrict__ NU,  const float* __restrict__ NV,
    float* __restrict__ out, int nev)
{
    __shared__ __align__(16) PostSmem sm;
    int tid = threadIdx.x;
    int base = blockIdx.x * EB;

    if (tid < EB) sm.s_t[tid] = (base + tid < nev) ? base + tid : -1;
    __syncthreads();

    {   // gather + loss
        int ev = tid >> 4, j = tid & 15;
        int t = sm.s_t[ev];
        float4 a = make_float4(0, 0, 0, 0), b = a, c = a, d = a;
        if (t >= 0) {
            int pu = prevu[t], pi = previ[t];
            const float4* up = (const float4*)(pu < 0 ?
                U0 + (size_t)uids[t] * EMB : NU + (size_t)pu * EMB);
            const float4* vp = (const float4*)(pi < 0 ?
                V0 + (size_t)iids[t] * EMB : NV + (size_t)pi * EMB);
            a = up[2 * j]; b = up[2 * j + 1];
            c = vp[2 * j]; d = vp[2 * j + 1];
            *(float4*)&sm.xu[ev][8 * j]     = a;
            *(float4*)&sm.xu[ev][8 * j + 4] = b;
            *(float4*)&sm.xv[ev][8 * j]     = c;
            *(float4*)&sm.xv[ev][8 * j + 4] = d;
        }
        float dp = a.x * c.x + a.y * c.y + a.z * c.z + a.w * c.w
                 + b.x * d.x + b.y * d.y + b.z * d.z + b.w * d.w;
        dp += __shfl_xor(dp, 1); dp += __shfl_xor(dp, 2);
        dp += __shfl_xor(dp, 4); dp += __shfl_xor(dp, 8);
        if (j == 0 && t >= 0)
            out[2 * (size_t)t] = -logf(softplusf_(dp) + 1e-10f);
    }

    // T1: h1 = relu(T1w @ [u;v] + b)
    int row = tid >> 2, evq = tid & 3;
    #pragma unroll 1
    for (int m = 0; m < 2; ++m) {
        float bb = T1b[m * 64 + row];
        float4 a4 = make_float4(bb, bb, bb, bb);
        a4 = gemm_piece(T1w + (size_t)(m * 64) * 256,       64, sm.xu, sm.wt, tid, a4);
        a4 = gemm_piece(T1w + (size_t)(m * 64) * 256 + 128, 64, sm.xv, sm.wt, tid, a4);
        sm.h1[evq * 4 + 0][m * 64 + row] = fmaxf(a4.x, 0.f);
        sm.h1[evq * 4 + 1][m * 64 + row] = fmaxf(a4.y, 0.f);
        sm.h1[evq * 4 + 2][m * 64 + row] = fmaxf(a4.z, 0.f);
        sm.h1[evq * 4 + 3][m * 64 + row] = fmaxf(a4.w, 0.f);
    }
    __syncthreads();

    // T2: h2 = relu(T2w @ h1 + b)
    {
        const float4* s2 = (const float4*)T2w;
        #pragma unroll
        for (int i = 0; i < 4; ++i) {
            int q = i * 256 + tid;
            int r = q >> 5, c = (q & 31) << 2;
            float4 w = s2[q];
            *(float4*)&sm.wt[r][c] = w;
        }
        __syncthreads();
        int r2 = tid >> 3, evp = tid & 7;
        float acc0 = T2b[r2], acc1 = T2b[r2];
        const float4* wr = (const float4*)&sm.wt[r2][0];
        const float4* xa = (const float4*)&sm.h1[evp][0];
        const float4* xb = (const float4*)&sm.h1[evp + 8][0];
        #pragma unroll
        for (int k = 0; k < 32; ++k) {
            float4 w = wr[k], p = xa[k], q4 = xb[k];
            acc0 = fmaf(w.x, p.x, acc0);  acc0 = fmaf(w.y, p.y, acc0);
            acc0 = fmaf(w.z, p.z, acc0);  acc0 = fmaf(w.w, p.w, acc0);
            acc1 = fmaf(w.x, q4.x, acc1); acc1 = fmaf(w.y, q4.y, acc1);
            acc1 = fmaf(w.z, q4.z, acc1); acc1 = fmaf(w.w, q4.w, acc1);
        }
        sm.h2[evp][r2]     = fmaxf(acc0, 0.f);
        sm.h2[evp + 8][r2] = fmaxf(acc1, 0.f);
        __syncthreads();
    }

    // T3 + sigmoid
    {
        int ev = tid >> 4, j = tid & 15;
        float p = T3w[2 * j] * sm.h2[ev][2 * j] + T3w[2 * j + 1] * sm.h2[ev][2 * j + 1];
        p += __shfl_xor(p, 1); p += __shfl_xor(p, 2);
        p += __shfl_xor(p, 4); p += __shfl_xor(p, 8);
        int t = sm.s_t[ev];
        if (j == 0 && t >= 0)
            out[2 * (size_t)t + 1] = sigmoidf_(p + T3b[0]);
    }
}

// ---------------------------------------------------------------------------
extern "C" void kernel_launch(void* const* d_in, const int* in_sizes, int n_in,
                              void* d_out, int out_size, void* d_ws, size_t ws_size,
                              hipStream_t stream)
{
    const float* U0  = (const float*)d_in[0];
    const float* V0  = (const float*)d_in[1];
    const float* Wui = (const float*)d_in[2];
    const float* Wuh = (const float*)d_in[3];
    const float* bui = (const float*)d_in[4];
    const float* buh = (const float*)d_in[5];
    const float* Wii = (const float*)d_in[6];
    const float* Wih = (const float*)d_in[7];
    const float* bii = (const float*)d_in[8];
    const float* bih = (const float*)d_in[9];
    const float* T1w = (const float*)d_in[10];
    const float* T1b = (const float*)d_in[11];
    const float* T2w = (const float*)d_in[12];
    const float* T2b = (const float*)d_in[13];
    const float* T3w = (const float*)d_in[14];
    const float* T3b = (const float*)d_in[15];
    const int* uids  = (const int*)d_in[16];
    const int* iids  = (const int*)d_in[17];
    int nev = in_sizes[16];

    int* base = (int*)d_ws;
    int* prevu     = base;                 // MAXEV
    int* previ     = base + MAXEV;         // MAXEV
    int* l0order   = base + 2 * MAXEV;     // MAXEV
    int* tailOrder = base + 3 * MAXEV;     // MAXEV
    int* compStart = base + 4 * MAXEV;     // MAXEV+2
    Hdr* hdr       = (Hdr*)(base + 5 * MAXEV + 4);
    float* NU = (float*)((char*)d_ws + (128 << 10));   // MAXEV*EMB floats
    float* NV = NU + (size_t)MAXEV * EMB;
    float* out = (float*)d_out;

    prev_kernel<<<nev, 64, 0, stream>>>(uids, iids, prevu, previ, nev);
    setup_kernel<<<1, 1024, 0, stream>>>(prevu, previ, l0order, tailOrder,
                                         compStart, hdr, nev);
    gemm_l0_kernel<<<256, 256, 0, stream>>>(
        U0, V0, Wui, Wuh, bui, buh, Wii, Wih, bii, bih,
        uids, iids, l0order, hdr, NU, NV);
    tail_kernel<<<512, 256, 0, stream>>>(
        U0, V0, Wui, Wuh, bui, buh, Wii, Wih, bii, bih,
        uids, iids, prevu, previ, tailOrder, compStart, hdr, NU, NV);

    int pblocks = (nev + EB - 1) / EB;
    post_kernel<<<pblocks, 256, 0, stream>>>(
        U0, V0, T1w, T1b, T2w, T2b, T3w, T3b,
        uids, iids, prevu, previ, NU, NV, out, nev);
}

// Round 4
// 220.699 us; speedup vs baseline: 3.0527x; 1.2373x over previous
//
#include <hip/hip_runtime.h>
#include <math.h>

#define EMB 128
#define PADW 132            // padded LDS row stride (floats) for gemm_piece/post
#define MAXEV 4096
#define EB 16               // events per group in post_kernel

struct Hdr { int nl0; int ncomp; };

__device__ __forceinline__ float sigmoidf_(float x) { return 1.0f / (1.0f + expf(-x)); }
__device__ __forceinline__ float softplusf_(float x) {
    return (x > 0.f) ? x + log1pf(expf(-x)) : log1pf(expf(x));
}

// ---------------------------------------------------------------------------
// Kernel 1: most recent earlier event with same user / item id.
// ---------------------------------------------------------------------------
__global__ __launch_bounds__(64) void prev_kernel(
    const int* __restrict__ uids, const int* __restrict__ iids,
    int* __restrict__ prevu, int* __restrict__ previ, int nev)
{
    int t = blockIdx.x;
    if (t >= nev) return;
    int lane = threadIdx.x;
    int myu = uids[t], myi = iids[t];
    int bu = -1, bi = -1;
    for (int j = lane; j < t; j += 64) {
        if (uids[j] == myu) bu = j;
        if (iids[j] == myi) bi = j;
    }
    for (int off = 32; off; off >>= 1) {
        bu = max(bu, __shfl_xor(bu, off));
        bi = max(bi, __shfl_xor(bi, off));
    }
    if (lane == 0) { prevu[t] = bu; previ[t] = bi; }
}

// ---------------------------------------------------------------------------
// Kernel 2 (single block): connected components over prev edges, partition
// into level-0 (no preds) vs tail, sort tail by (component, t).
// ---------------------------------------------------------------------------
__global__ __launch_bounds__(1024) void setup_kernel(
    const int* __restrict__ prevu, const int* __restrict__ previ,
    int* __restrict__ l0order, int* __restrict__ tailOrder,
    int* __restrict__ compStart, Hdr* __restrict__ hdr, int nev)
{
    __shared__ int lab[MAXEV];
    __shared__ int tmpT[MAXEV];
    __shared__ int skey[MAXEV];
    __shared__ int schanged, sntail, snl0;

    int tid = threadIdx.x;
    for (int t = tid; t < nev; t += 1024) lab[t] = t;
    if (tid == 0) { sntail = 0; snl0 = 0; }
    __syncthreads();

    for (int it = 0; it < nev; ++it) {
        if (tid == 0) schanged = 0;
        __syncthreads();
        for (int t = tid; t < nev; t += 1024) {
            int m = lab[t];
            int pu = prevu[t], pi = previ[t];
            if (pu >= 0) m = min(m, lab[pu]);
            if (pi >= 0) m = min(m, lab[pi]);
            if (m < lab[t]) { atomicMin(&lab[t], m); schanged = 1; }
            if (pu >= 0 && m < lab[pu]) { atomicMin(&lab[pu], m); schanged = 1; }
            if (pi >= 0 && m < lab[pi]) { atomicMin(&lab[pi], m); schanged = 1; }
        }
        __syncthreads();
        if (!schanged) break;
        __syncthreads();
    }

    for (int t = tid; t < nev; t += 1024) {
        if (prevu[t] >= 0 || previ[t] >= 0) {
            int i = atomicAdd(&sntail, 1);
            tmpT[i] = t;
        } else {
            int i = atomicAdd(&snl0, 1);
            l0order[i] = t;
        }
    }
    __syncthreads();
    int ntail = sntail;

    for (int i = tid; i < ntail; i += 1024)
        skey[i] = (lab[tmpT[i]] << 12) | tmpT[i];
    __syncthreads();

    for (int i = tid; i < ntail; i += 1024) {
        int k = skey[i], r = 0;
        for (int j = 0; j < ntail; ++j) r += (skey[j] < k);
        tailOrder[r] = tmpT[i];
        lab[r] = k;
    }
    __syncthreads();

    if (tid == 0) {
        int nc = 0;
        for (int i = 0; i < ntail; ++i)
            if (i == 0 || (lab[i] >> 12) != (lab[i - 1] >> 12))
                compStart[nc++] = i;
        compStart[nc] = ntail;
        hdr->ncomp = nc;
        hdr->nl0 = snl0;
    }
}

// ---------------------------------------------------------------------------
// Kernel 3a: gather level-0 event inputs into dense Xu/Xv [NP64,128],
// zero-padding to a multiple of 64 rows.
// ---------------------------------------------------------------------------
__global__ __launch_bounds__(256) void gather_kernel(
    const float* __restrict__ U0, const float* __restrict__ V0,
    const int* __restrict__ uids, const int* __restrict__ iids,
    const int* __restrict__ l0order, const Hdr* __restrict__ hdr,
    float* __restrict__ Xu, float* __restrict__ Xv)
{
    int nl0 = hdr->nl0;
    int NP64 = (nl0 + 63) & ~63;
    int sub = threadIdx.x >> 5;       // 0..7 events per block
    int lane = threadIdx.x & 31;      // 32 float4 per row
    int e = blockIdx.x * 8 + sub;
    if (e >= NP64) return;
    float4* xu = (float4*)(Xu + (size_t)e * EMB);
    float4* xv = (float4*)(Xv + (size_t)e * EMB);
    if (e < nl0) {
        int t = l0order[e];
        const float4* up = (const float4*)(U0 + (size_t)uids[t] * EMB);
        const float4* vp = (const float4*)(V0 + (size_t)iids[t] * EMB);
        xu[lane] = up[lane];
        xv[lane] = vp[lane];
    } else {
        float4 zz = make_float4(0.f, 0.f, 0.f, 0.f);
        xu[lane] = zz;
        xv[lane] = zz;
    }
}

// ---------------------------------------------------------------------------
// Kernel 3b: gate GEMM. G_u = Xu @ [Wuh;Wii]^T, G_v = Xv @ [Wui;Wih]^T.
// Tile: 64 events x 64 rows, K=128 in two halves. LDS 2x16KB, XOR-swizzled
// (f4 idx = row*16 + (c4 ^ ((row>>2)&7))) so 16-distinct-row ds_read_b128
// is ~2-way. Thread: 4 events x 4 rows register tile.
// ---------------------------------------------------------------------------
__global__ __launch_bounds__(256, 4) void gate_gemm_kernel(
    const float* __restrict__ Xu, const float* __restrict__ Xv,
    const float* __restrict__ Wuh, const float* __restrict__ Wii,
    const float* __restrict__ Wui, const float* __restrict__ Wih,
    const Hdr* __restrict__ hdr,
    float* __restrict__ Gu, float* __restrict__ Gv)
{
    __shared__ float4 Xs[1024];
    __shared__ float4 Ws[1024];
    int nl0 = hdr->nl0;
    int NP64 = (nl0 + 63) & ~63;
    int ev0 = blockIdx.x * 64;
    if (ev0 >= NP64) return;
    int z = blockIdx.z;
    int j = blockIdx.y;                    // 0..11 (12 x 64 = 768 gate rows)
    const float* X  = z ? Xv : Xu;
    const float* W1 = z ? Wui : Wuh;
    const float* W2 = z ? Wih : Wii;
    float* G = z ? Gv : Gu;
    const float* Wsrc = (j < 6) ? W1 : W2;
    int row0 = ((j < 6) ? j : j - 6) * 64;

    int tid = threadIdx.x;
    int e0 = (tid >> 4) * 4, r0 = (tid & 15) * 4;
    int sx = (e0 >> 2) & 7, sw = (r0 >> 2) & 7;
    float acc[4][4] = {};
    const float4* X4 = (const float4*)X;
    const float4* W4 = (const float4*)Wsrc;

    for (int kh = 0; kh < 2; ++kh) {
        __syncthreads();
        #pragma unroll
        for (int p = 0; p < 4; ++p) {
            int q = p * 256 + tid;
            int r = q >> 4, c4 = q & 15;
            int sr = (r >> 2) & 7;
            Xs[r * 16 + (c4 ^ sr)] = X4[(size_t)(ev0 + r) * 32 + kh * 16 + c4];
            Ws[r * 16 + (c4 ^ sr)] = W4[(size_t)(row0 + r) * 32 + kh * 16 + c4];
        }
        __syncthreads();
        #pragma unroll 4
        for (int k4 = 0; k4 < 16; ++k4) {
            float4 xa[4], wb[4];
            #pragma unroll
            for (int i = 0; i < 4; ++i) xa[i] = Xs[(e0 + i) * 16 + (k4 ^ sx)];
            #pragma unroll
            for (int jj = 0; jj < 4; ++jj) wb[jj] = Ws[(r0 + jj) * 16 + (k4 ^ sw)];
            #pragma unroll
            for (int i = 0; i < 4; ++i) {
                #pragma unroll
                for (int jj = 0; jj < 4; ++jj) {
                    acc[i][jj] = fmaf(xa[i].x, wb[jj].x, acc[i][jj]);
                    acc[i][jj] = fmaf(xa[i].y, wb[jj].y, acc[i][jj]);
                    acc[i][jj] = fmaf(xa[i].z, wb[jj].z, acc[i][jj]);
                    acc[i][jj] = fmaf(xa[i].w, wb[jj].w, acc[i][jj]);
                }
            }
        }
    }
    int col0 = j * 64 + r0;
    #pragma unroll
    for (int i = 0; i < 4; ++i) {
        float4 v = make_float4(acc[i][0], acc[i][1], acc[i][2], acc[i][3]);
        *(float4*)&G[(size_t)(ev0 + e0 + i) * 768 + col0] = v;
    }
}

// ---------------------------------------------------------------------------
// Kernel 3c: gate combine -> NU/NV for level-0 events.
// G_v = [Wui@v ; Wih@v], G_u = [Wuh@u ; Wii@u].
// ---------------------------------------------------------------------------
__global__ __launch_bounds__(256) void combine_kernel(
    const float* __restrict__ Gu, const float* __restrict__ Gv,
    const float* __restrict__ Xu, const float* __restrict__ Xv,
    const float* __restrict__ bui, const float* __restrict__ buh,
    const float* __restrict__ bii, const float* __restrict__ bih,
    const int* __restrict__ l0order, const Hdr* __restrict__ hdr,
    float* __restrict__ NU, float* __restrict__ NV)
{
    int nl0 = hdr->nl0;
    int e = blockIdx.x * 2 + (threadIdx.x >> 7);
    int rr = threadIdx.x & 127;
    if (e >= nl0) return;
    int t = l0order[e];
    const float* gu = Gu + (size_t)e * 768;
    const float* gv = Gv + (size_t)e * 768;
    // user cell: x=v, h=u
    float r = sigmoidf_(gv[rr] + bui[rr] + gu[rr] + buh[rr]);
    float zg = sigmoidf_(gv[128 + rr] + bui[128 + rr] + gu[128 + rr] + buh[128 + rr]);
    float n = tanhf(gv[256 + rr] + bui[256 + rr] + r * (gu[256 + rr] + buh[256 + rr]));
    float u = Xu[(size_t)e * EMB + rr];
    NU[(size_t)t * EMB + rr] = (1.f - zg) * n + zg * u;
    // item cell: x=u, h=v
    float r2 = sigmoidf_(gu[384 + rr] + bii[rr] + gv[384 + rr] + bih[rr]);
    float z2 = sigmoidf_(gu[512 + rr] + bii[128 + rr] + gv[512 + rr] + bih[128 + rr]);
    float n2 = tanhf(gu[640 + rr] + bii[256 + rr] + r2 * (gv[640 + rr] + bih[256 + rr]));
    float v = Xv[(size_t)e * EMB + rr];
    NV[(size_t)t * EMB + rr] = (1.f - z2) * n2 + z2 * v;
}

// ---------------------------------------------------------------------------
// GEMM piece (used by post_kernel): acc[e] += sum_k W[row][k]*x[ev][k]
// for a 64-row x 16-event tile, K=128.
// ---------------------------------------------------------------------------
static __device__ __attribute__((noinline)) float4 gemm_piece(
    const float* __restrict__ Wbase, int strideF4,
    const float (*__restrict__ x)[PADW],
    float (*__restrict__ wt)[PADW],
    int tid, float4 acc)
{
    __syncthreads();
    const float4* src = (const float4*)Wbase;
    #pragma unroll
    for (int i = 0; i < 8; ++i) {
        int q = i * 256 + tid;
        int r = q >> 5, c = (q & 31) << 2;
        float4 w = src[(size_t)r * strideF4 + (q & 31)];
        *(float4*)&wt[r][c] = w;
    }
    __syncthreads();
    int row = tid >> 2, evq = tid & 3;
    const float4* wr = (const float4*)&wt[row][0];
    const float4* x0 = (const float4*)&x[evq * 4 + 0][0];
    const float4* x1 = (const float4*)&x[evq * 4 + 1][0];
    const float4* x2 = (const float4*)&x[evq * 4 + 2][0];
    const float4* x3 = (const float4*)&x[evq * 4 + 3][0];
    #pragma unroll
    for (int k = 0; k < EMB / 4; ++k) {
        float4 w = wr[k];
        float4 a = x0[k];
        acc.x = fmaf(w.x, a.x, acc.x); acc.x = fmaf(w.y, a.y, acc.x);
        acc.x = fmaf(w.z, a.z, acc.x); acc.x = fmaf(w.w, a.w, acc.x);
        float4 b = x1[k];
        acc.y = fmaf(w.x, b.x, acc.y); acc.y = fmaf(w.y, b.y, acc.y);
        acc.y = fmaf(w.z, b.z, acc.y); acc.y = fmaf(w.w, b.w, acc.y);
        float4 c = x2[k];
        acc.z = fmaf(w.x, c.x, acc.z); acc.z = fmaf(w.y, c.y, acc.z);
        acc.z = fmaf(w.z, c.z, acc.z); acc.z = fmaf(w.w, c.w, acc.z);
        float4 d = x3[k];
        acc.w = fmaf(w.x, d.x, acc.w); acc.w = fmaf(w.y, d.y, acc.w);
        acc.w = fmaf(w.z, d.z, acc.w); acc.w = fmaf(w.w, d.w, acc.w);
    }
    return acc;
}

struct TailSmem {
    float su[EMB];
    float sv[EMB];
    float gg[1536];
};

// ---------------------------------------------------------------------------
// Kernel 4: dependent events, one block per component, sequential in t.
// ---------------------------------------------------------------------------
__global__ __launch_bounds__(256) void tail_kernel(
    const float* __restrict__ U0,  const float* __restrict__ V0,
    const float* __restrict__ Wui, const float* __restrict__ Wuh,
    const float* __restrict__ bui, const float* __restrict__ buh,
    const float* __restrict__ Wii, const float* __restrict__ Wih,
    const float* __restrict__ bii, const float* __restrict__ bih,
    const int* __restrict__ uids,  const int* __restrict__ iids,
    const int* __restrict__ prevu, const int* __restrict__ previ,
    const int* __restrict__ tailOrder, const int* __restrict__ compStart,
    const Hdr* __restrict__ hdr,
    float* __restrict__ NU, float* __restrict__ NV)
{
    __shared__ __align__(16) TailSmem sm;
    int tid = threadIdx.x;
    int ncomp = hdr->ncomp;

    for (int c = blockIdx.x; c < ncomp; c += gridDim.x) {
        int kb = compStart[c], ke = compStart[c + 1];
        for (int k = kb; k < ke; ++k) {
            int t = tailOrder[k];
            int pu = prevu[t], pi = previ[t];
            const float* up = (pu < 0) ? U0 + (size_t)uids[t] * EMB : NU + (size_t)pu * EMB;
            const float* vp = (pi < 0) ? V0 + (size_t)iids[t] * EMB : NV + (size_t)pi * EMB;
            __syncthreads();
            if (tid < EMB) sm.su[tid] = up[tid];
            else           sm.sv[tid - EMB] = vp[tid - EMB];
            __syncthreads();

            int g = tid >> 4, j = tid & 15;
            #pragma unroll 4
            for (int pp = 0; pp < 96; ++pp) {
                int rg = pp * 16 + g;
                int mat = rg / 384;
                int r = rg - mat * 384;
                const float* W = (mat == 0) ? Wui : (mat == 1) ? Wuh : (mat == 2) ? Wii : Wih;
                const float* x = (mat == 1 || mat == 2) ? sm.su : sm.sv;
                const float4* W4 = (const float4*)(W + (size_t)r * EMB);
                const float4* x4 = (const float4*)x;
                float4 w0 = W4[2 * j], w1 = W4[2 * j + 1];
                float4 xa = x4[2 * j], xb = x4[2 * j + 1];
                float s;
                s  = w0.x * xa.x;        s = fmaf(w0.y, xa.y, s);
                s = fmaf(w0.z, xa.z, s); s = fmaf(w0.w, xa.w, s);
                s = fmaf(w1.x, xb.x, s); s = fmaf(w1.y, xb.y, s);
                s = fmaf(w1.z, xb.z, s); s = fmaf(w1.w, xb.w, s);
                s += __shfl_xor(s, 1); s += __shfl_xor(s, 2);
                s += __shfl_xor(s, 4); s += __shfl_xor(s, 8);
                if (j == 0) sm.gg[rg] = s;
            }
            __syncthreads();

            if (tid < EMB) {
                int e = tid;
                float r_ = sigmoidf_(sm.gg[e] + bui[e] + sm.gg[384 + e] + buh[e]);
                float z_ = sigmoidf_(sm.gg[128 + e] + bui[128 + e] + sm.gg[512 + e] + buh[128 + e]);
                float n_ = tanhf(sm.gg[256 + e] + bui[256 + e] + r_ * (sm.gg[640 + e] + buh[256 + e]));
                NU[(size_t)t * EMB + e] = (1.f - z_) * n_ + z_ * sm.su[e];
            } else {
                int e = tid - EMB;
                float r_ = sigmoidf_(sm.gg[768 + e] + bii[e] + sm.gg[1152 + e] + bih[e]);
                float z_ = sigmoidf_(sm.gg[896 + e] + bii[128 + e] + sm.gg[1280 + e] + bih[128 + e]);
                float n_ = tanhf(sm.gg[1024 + e] + bii[256 + e] + r_ * (sm.gg[1408 + e] + bih[256 + e]));
                NV[(size_t)t * EMB + e] = (1.f - z_) * n_ + z_ * sm.sv[e];
            }
        }
    }
}

struct PostSmem {
    float xu[EB][PADW];
    float xv[EB][PADW];
    float wt[64][PADW];
    float h1[EB][PADW];
    float h2[EB][36];
    int   s_t[EB];
};

// ---------------------------------------------------------------------------
// Kernel 5: loss + MLP branch for all events (reads event INPUT u,v).
// ---------------------------------------------------------------------------
__global__ __launch_bounds__(256) void post_kernel(
    const float* __restrict__ U0,  const float* __restrict__ V0,
    const float* __restrict__ T1w, const float* __restrict__ T1b,
    const float* __restrict__ T2w, const float* __restrict__ T2b,
    const float* __restrict__ T3w, const float* __restrict__ T3b,
    const int* __restrict__ uids,  const int* __restrict__ iids,
    const int* __restrict__ prevu, const int* __restrict__ previ,
    const float* __restrict__ NU,  const float* __restrict__ NV,
    float* __restrict__ out, int nev)
{
    __shared__ __align__(16) PostSmem sm;
    int tid = threadIdx.x;
    int base = blockIdx.x * EB;

    if (tid < EB) sm.s_t[tid] = (base + tid < nev) ? base + tid : -1;
    __syncthreads();

    {   // gather + loss
        int ev = tid >> 4, j = tid & 15;
        int t = sm.s_t[ev];
        float4 a = make_float4(0, 0, 0, 0), b = a, c = a, d = a;
        if (t >= 0) {
            int pu = prevu[t], pi = previ[t];
            const float4* up = (const float4*)(pu < 0 ?
                U0 + (size_t)uids[t] * EMB : NU + (size_t)pu * EMB);
            const float4* vp = (const float4*)(pi < 0 ?
                V0 + (size_t)iids[t] * EMB : NV + (size_t)pi * EMB);
            a = up[2 * j]; b = up[2 * j + 1];
            c = vp[2 * j]; d = vp[2 * j + 1];
            *(float4*)&sm.xu[ev][8 * j]     = a;
            *(float4*)&sm.xu[ev][8 * j + 4] = b;
            *(float4*)&sm.xv[ev][8 * j]     = c;
            *(float4*)&sm.xv[ev][8 * j + 4] = d;
        }
        float dp = a.x * c.x + a.y * c.y + a.z * c.z + a.w * c.w
                 + b.x * d.x + b.y * d.y + b.z * d.z + b.w * d.w;
        dp += __shfl_xor(dp, 1); dp += __shfl_xor(dp, 2);
        dp += __shfl_xor(dp, 4); dp += __shfl_xor(dp, 8);
        if (j == 0 && t >= 0)
            out[2 * (size_t)t] = -logf(softplusf_(dp) + 1e-10f);
    }

    // T1: h1 = relu(T1w @ [u;v] + b)
    int row = tid >> 2, evq = tid & 3;
    #pragma unroll 1
    for (int m = 0; m < 2; ++m) {
        float bb = T1b[m * 64 + row];
        float4 a4 = make_float4(bb, bb, bb, bb);
        a4 = gemm_piece(T1w + (size_t)(m * 64) * 256,       64, sm.xu, sm.wt, tid, a4);
        a4 = gemm_piece(T1w + (size_t)(m * 64) * 256 + 128, 64, sm.xv, sm.wt, tid, a4);
        sm.h1[evq * 4 + 0][m * 64 + row] = fmaxf(a4.x, 0.f);
        sm.h1[evq * 4 + 1][m * 64 + row] = fmaxf(a4.y, 0.f);
        sm.h1[evq * 4 + 2][m * 64 + row] = fmaxf(a4.z, 0.f);
        sm.h1[evq * 4 + 3][m * 64 + row] = fmaxf(a4.w, 0.f);
    }
    __syncthreads();

    // T2: h2 = relu(T2w @ h1 + b)
    {
        const float4* s2 = (const float4*)T2w;
        #pragma unroll
        for (int i = 0; i < 4; ++i) {
            int q = i * 256 + tid;
            int r = q >> 5, c = (q & 31) << 2;
            float4 w = s2[q];
            *(float4*)&sm.wt[r][c] = w;
        }
        __syncthreads();
        int r2 = tid >> 3, evp = tid & 7;
        float acc0 = T2b[r2], acc1 = T2b[r2];
        const float4* wr = (const float4*)&sm.wt[r2][0];
        const float4* xa = (const float4*)&sm.h1[evp][0];
        const float4* xb = (const float4*)&sm.h1[evp + 8][0];
        #pragma unroll
        for (int k = 0; k < 32; ++k) {
            float4 w = wr[k], p = xa[k], q4 = xb[k];
            acc0 = fmaf(w.x, p.x, acc0);  acc0 = fmaf(w.y, p.y, acc0);
            acc0 = fmaf(w.z, p.z, acc0);  acc0 = fmaf(w.w, p.w, acc0);
            acc1 = fmaf(w.x, q4.x, acc1); acc1 = fmaf(w.y, q4.y, acc1);
            acc1 = fmaf(w.z, q4.z, acc1); acc1 = fmaf(w.w, q4.w, acc1);
        }
        sm.h2[evp][r2]     = fmaxf(acc0, 0.f);
        sm.h2[evp + 8][r2] = fmaxf(acc1, 0.f);
        __syncthreads();
    }

    // T3 + sigmoid
    {
        int ev = tid >> 4, j = tid & 15;
        float p = T3w[2 * j] * sm.h2[ev][2 * j] + T3w[2 * j + 1] * sm.h2[ev][2 * j + 1];
        p += __shfl_xor(p, 1); p += __shfl_xor(p, 2);
        p += __shfl_xor(p, 4); p += __shfl_xor(p, 8);
        int t = sm.s_t[ev];
        if (j == 0 && t >= 0)
            out[2 * (size_t)t + 1] = sigmoidf_(p + T3b[0]);
    }
}

// ---------------------------------------------------------------------------
extern "C" void kernel_launch(void* const* d_in, const int* in_sizes, int n_in,
                              void* d_out, int out_size, void* d_ws, size_t ws_size,
                              hipStream_t stream)
{
    const float* U0  = (const float*)d_in[0];
    const float* V0  = (const float*)d_in[1];
    const float* Wui = (const float*)d_in[2];
    const float* Wuh = (const float*)d_in[3];
    const float* bui = (const float*)d_in[4];
    const float* buh = (const float*)d_in[5];
    const float* Wii = (const float*)d_in[6];
    const float* Wih = (const float*)d_in[7];
    const float* bii = (const float*)d_in[8];
    const float* bih = (const float*)d_in[9];
    const float* T1w = (const float*)d_in[10];
    const float* T1b = (const float*)d_in[11];
    const float* T2w = (const float*)d_in[12];
    const float* T2b = (const float*)d_in[13];
    const float* T3w = (const float*)d_in[14];
    const float* T3b = (const float*)d_in[15];
    const int* uids  = (const int*)d_in[16];
    const int* iids  = (const int*)d_in[17];
    int nev = in_sizes[16];

    char* ws = (char*)d_ws;
    int* base = (int*)ws;
    int* prevu     = base;                 // MAXEV
    int* previ     = base + MAXEV;         // MAXEV
    int* l0order   = base + 2 * MAXEV;     // MAXEV
    int* tailOrder = base + 3 * MAXEV;     // MAXEV
    int* compStart = base + 4 * MAXEV;     // MAXEV+2
    Hdr* hdr       = (Hdr*)(base + 5 * MAXEV + 4);
    float* NU = (float*)(ws + (128 << 10));            // 2 MB
    float* NV = NU + (size_t)MAXEV * EMB;              // 2 MB
    float* Xu = NV + (size_t)MAXEV * EMB;              // 2 MB
    float* Xv = Xu + (size_t)MAXEV * EMB;              // 2 MB
    float* Gu = Xv + (size_t)MAXEV * EMB;              // 12.6 MB
    float* Gv = Gu + (size_t)MAXEV * 768;              // 12.6 MB
    float* out = (float*)d_out;

    prev_kernel<<<nev, 64, 0, stream>>>(uids, iids, prevu, previ, nev);
    setup_kernel<<<1, 1024, 0, stream>>>(prevu, previ, l0order, tailOrder,
                                         compStart, hdr, nev);
    gather_kernel<<<(MAXEV + 7) / 8, 256, 0, stream>>>(
        U0, V0, uids, iids, l0order, hdr, Xu, Xv);
    gate_gemm_kernel<<<dim3(MAXEV / 64, 12, 2), 256, 0, stream>>>(
        Xu, Xv, Wuh, Wii, Wui, Wih, hdr, Gu, Gv);
    combine_kernel<<<(MAXEV + 1) / 2, 256, 0, stream>>>(
        Gu, Gv, Xu, Xv, bui, buh, bii, bih, l0order, hdr, NU, NV);
    tail_kernel<<<512, 256, 0, stream>>>(
        U0, V0, Wui, Wuh, bui, buh, Wii, Wih, bii, bih,
        uids, iids, prevu, previ, tailOrder, compStart, hdr, NU, NV);
    post_kernel<<<(nev + EB - 1) / EB, 256, 0, stream>>>(
        U0, V0, T1w, T1b, T2w, T2b, T3w, T3b,
        uids, iids, prevu, previ, NU, NV, out, nev);
}

// Round 5
// 211.931 us; speedup vs baseline: 3.1790x; 1.0414x over previous
//
#include <hip/hip_runtime.h>
#include <math.h>

#define EMB 128
#define MAXEV 4096

struct Hdr { int nl0; int ntail; };

__device__ __forceinline__ float sigmoidf_(float x) { return 1.0f / (1.0f + expf(-x)); }
__device__ __forceinline__ float softplusf_(float x) {
    return (x > 0.f) ? x + log1pf(expf(-x)) : log1pf(expf(x));
}

// ---------------------------------------------------------------------------
// Kernel 1: most recent earlier event with same user / item id.
// ---------------------------------------------------------------------------
__global__ __launch_bounds__(64) void prev_kernel(
    const int* __restrict__ uids, const int* __restrict__ iids,
    int* __restrict__ prevu, int* __restrict__ previ, int nev)
{
    int t = blockIdx.x;
    if (t >= nev) return;
    int lane = threadIdx.x;
    int myu = uids[t], myi = iids[t];
    int bu = -1, bi = -1;
    for (int j = lane; j < t; j += 64) {
        if (uids[j] == myu) bu = j;
        if (iids[j] == myi) bi = j;
    }
    for (int off = 32; off; off >>= 1) {
        bu = max(bu, __shfl_xor(bu, off));
        bi = max(bi, __shfl_xor(bi, off));
    }
    if (lane == 0) { prevu[t] = bu; previ[t] = bi; }
}

// ---------------------------------------------------------------------------
// Kernel 2 (single block): partition into level-0 (no preds) vs tail;
// tail sorted ascending by t (needed for deadlock-free spin ordering).
// ---------------------------------------------------------------------------
__global__ __launch_bounds__(1024) void setup_kernel(
    const int* __restrict__ prevu, const int* __restrict__ previ,
    int* __restrict__ l0order, int* __restrict__ tailOrder,
    Hdr* __restrict__ hdr, int nev)
{
    __shared__ int tmpT[MAXEV];
    __shared__ int sntail, snl0;
    int tid = threadIdx.x;
    if (tid == 0) { sntail = 0; snl0 = 0; }
    __syncthreads();
    for (int t = tid; t < nev; t += 1024) {
        if (prevu[t] >= 0 || previ[t] >= 0) tmpT[atomicAdd(&sntail, 1)] = t;
        else                                 l0order[atomicAdd(&snl0, 1)] = t;
    }
    __syncthreads();
    int ntail = sntail;
    for (int i = tid; i < ntail; i += 1024) {   // rank sort by t (unique keys)
        int k = tmpT[i], r = 0;
        for (int j = 0; j < ntail; ++j) r += (tmpT[j] < k);
        tailOrder[r] = k;
    }
    if (tid == 0) { hdr->nl0 = snl0; hdr->ntail = ntail; }
}

// ---------------------------------------------------------------------------
// Kernel 3a: gather level-0 inputs into dense Xu/Xv [NP64,128], zero-padded.
// ---------------------------------------------------------------------------
__global__ __launch_bounds__(256) void gather_kernel(
    const float* __restrict__ U0, const float* __restrict__ V0,
    const int* __restrict__ uids, const int* __restrict__ iids,
    const int* __restrict__ l0order, const Hdr* __restrict__ hdr,
    float* __restrict__ Xu, float* __restrict__ Xv)
{
    int nl0 = hdr->nl0;
    int NP64 = (nl0 + 63) & ~63;
    int sub = threadIdx.x >> 5;
    int lane = threadIdx.x & 31;
    int e = blockIdx.x * 8 + sub;
    if (e >= NP64) return;
    float4* xu = (float4*)(Xu + (size_t)e * EMB);
    float4* xv = (float4*)(Xv + (size_t)e * EMB);
    if (e < nl0) {
        int t = l0order[e];
        const float4* up = (const float4*)(U0 + (size_t)uids[t] * EMB);
        const float4* vp = (const float4*)(V0 + (size_t)iids[t] * EMB);
        xu[lane] = up[lane];
        xv[lane] = vp[lane];
    } else {
        float4 zz = make_float4(0.f, 0.f, 0.f, 0.f);
        xu[lane] = zz;
        xv[lane] = zz;
    }
}

// ---------------------------------------------------------------------------
// Kernel 3b: gate GEMM. G_u = Xu @ [Wuh;Wii]^T, G_v = Xv @ [Wui;Wih]^T.
// 64x64 tile, K=128 in two halves, XOR-swizzled LDS, 4x4 register tile.
// ---------------------------------------------------------------------------
__global__ __launch_bounds__(256, 4) void gate_gemm_kernel(
    const float* __restrict__ Xu, const float* __restrict__ Xv,
    const float* __restrict__ Wuh, const float* __restrict__ Wii,
    const float* __restrict__ Wui, const float* __restrict__ Wih,
    const Hdr* __restrict__ hdr,
    float* __restrict__ Gu, float* __restrict__ Gv)
{
    __shared__ float4 Xs[1024];
    __shared__ float4 Ws[1024];
    int nl0 = hdr->nl0;
    int NP64 = (nl0 + 63) & ~63;
    int ev0 = blockIdx.x * 64;
    if (ev0 >= NP64) return;
    int z = blockIdx.z;
    int j = blockIdx.y;
    const float* X  = z ? Xv : Xu;
    const float* W1 = z ? Wui : Wuh;
    const float* W2 = z ? Wih : Wii;
    float* G = z ? Gv : Gu;
    const float* Wsrc = (j < 6) ? W1 : W2;
    int row0 = ((j < 6) ? j : j - 6) * 64;

    int tid = threadIdx.x;
    int e0 = (tid >> 4) * 4, r0 = (tid & 15) * 4;
    int sx = (e0 >> 2) & 7, sw = (r0 >> 2) & 7;
    float acc[4][4] = {};
    const float4* X4 = (const float4*)X;
    const float4* W4 = (const float4*)Wsrc;

    for (int kh = 0; kh < 2; ++kh) {
        __syncthreads();
        #pragma unroll
        for (int p = 0; p < 4; ++p) {
            int q = p * 256 + tid;
            int r = q >> 4, c4 = q & 15;
            int sr = (r >> 2) & 7;
            Xs[r * 16 + (c4 ^ sr)] = X4[(size_t)(ev0 + r) * 32 + kh * 16 + c4];
            Ws[r * 16 + (c4 ^ sr)] = W4[(size_t)(row0 + r) * 32 + kh * 16 + c4];
        }
        __syncthreads();
        #pragma unroll 4
        for (int k4 = 0; k4 < 16; ++k4) {
            float4 xa[4], wb[4];
            #pragma unroll
            for (int i = 0; i < 4; ++i) xa[i] = Xs[(e0 + i) * 16 + (k4 ^ sx)];
            #pragma unroll
            for (int jj = 0; jj < 4; ++jj) wb[jj] = Ws[(r0 + jj) * 16 + (k4 ^ sw)];
            #pragma unroll
            for (int i = 0; i < 4; ++i) {
                #pragma unroll
                for (int jj = 0; jj < 4; ++jj) {
                    acc[i][jj] = fmaf(xa[i].x, wb[jj].x, acc[i][jj]);
                    acc[i][jj] = fmaf(xa[i].y, wb[jj].y, acc[i][jj]);
                    acc[i][jj] = fmaf(xa[i].z, wb[jj].z, acc[i][jj]);
                    acc[i][jj] = fmaf(xa[i].w, wb[jj].w, acc[i][jj]);
                }
            }
        }
    }
    int col0 = j * 64 + r0;
    #pragma unroll
    for (int i = 0; i < 4; ++i) {
        float4 v = make_float4(acc[i][0], acc[i][1], acc[i][2], acc[i][3]);
        *(float4*)&G[(size_t)(ev0 + e0 + i) * 768 + col0] = v;
    }
}

// ---------------------------------------------------------------------------
// Kernel 3c: gate combine -> NU/NV for level-0 events; sets done flags.
// ---------------------------------------------------------------------------
__global__ __launch_bounds__(256) void combine_kernel(
    const float* __restrict__ Gu, const float* __restrict__ Gv,
    const float* __restrict__ Xu, const float* __restrict__ Xv,
    const float* __restrict__ bui, const float* __restrict__ buh,
    const float* __restrict__ bii, const float* __restrict__ bih,
    const int* __restrict__ l0order, const Hdr* __restrict__ hdr,
    float* __restrict__ NU, float* __restrict__ NV,
    int* __restrict__ flags)
{
    int nl0 = hdr->nl0;
    int e = blockIdx.x * 2 + (threadIdx.x >> 7);
    int rr = threadIdx.x & 127;
    if (e >= nl0) return;
    int t = l0order[e];
    const float* gu = Gu + (size_t)e * 768;
    const float* gv = Gv + (size_t)e * 768;
    float r = sigmoidf_(gv[rr] + bui[rr] + gu[rr] + buh[rr]);
    float zg = sigmoidf_(gv[128 + rr] + bui[128 + rr] + gu[128 + rr] + buh[128 + rr]);
    float n = tanhf(gv[256 + rr] + bui[256 + rr] + r * (gu[256 + rr] + buh[256 + rr]));
    float u = Xu[(size_t)e * EMB + rr];
    NU[(size_t)t * EMB + rr] = (1.f - zg) * n + zg * u;
    float r2 = sigmoidf_(gu[384 + rr] + bii[rr] + gv[384 + rr] + bih[rr]);
    float z2 = sigmoidf_(gu[512 + rr] + bii[128 + rr] + gv[512 + rr] + bih[128 + rr]);
    float n2 = tanhf(gu[640 + rr] + bii[256 + rr] + r2 * (gv[640 + rr] + bih[256 + rr]));
    float v = Xv[(size_t)e * EMB + rr];
    NV[(size_t)t * EMB + rr] = (1.f - z2) * n2 + z2 * v;
    if (rr == 0) flags[t] = 1;    // visible to tail via kernel boundary
}

// ---------------------------------------------------------------------------
// Kernel 4: dependent events via spin-flag dataflow. Grid is co-resident
// (sized by occupancy at launch); events sorted by t; deps have smaller t.
// Deadlock-free: the earliest unfinished event's deps are all done/running.
// Gate compute: 16-lane groups x 8-row batches (16 loads in flight).
// ---------------------------------------------------------------------------
__global__ __launch_bounds__(256) void tail_kernel(
    const float* __restrict__ U0,  const float* __restrict__ V0,
    const float* __restrict__ Wui, const float* __restrict__ Wuh,
    const float* __restrict__ bui, const float* __restrict__ buh,
    const float* __restrict__ Wii, const float* __restrict__ Wih,
    const float* __restrict__ bii, const float* __restrict__ bih,
    const int* __restrict__ uids,  const int* __restrict__ iids,
    const int* __restrict__ prevu, const int* __restrict__ previ,
    const int* __restrict__ tailOrder, const Hdr* __restrict__ hdr,
    int* __restrict__ flags,
    float* __restrict__ NU, float* __restrict__ NV)
{
    __shared__ __align__(16) float su[EMB];
    __shared__ __align__(16) float sv[EMB];
    __shared__ float gg[1536];
    int tid = threadIdx.x;
    int ntail = hdr->ntail;

    for (int k = blockIdx.x; k < ntail; k += gridDim.x) {
        int t = tailOrder[k];
        int pu = prevu[t], pi = previ[t];

        if (tid == 0) {   // acquire both predecessor flags
            int fu = (pu < 0), fi = (pi < 0);
            while (!(fu && fi)) {
                if (!fu && atomicAdd(&flags[pu], 0)) fu = 1;
                if (!fi && atomicAdd(&flags[pi], 0)) fi = 1;
            }
            __threadfence();
        }
        __syncthreads();

        const float* up = (pu < 0) ? U0 + (size_t)uids[t] * EMB : NU + (size_t)pu * EMB;
        const float* vp = (pi < 0) ? V0 + (size_t)iids[t] * EMB : NV + (size_t)pi * EMB;
        if (tid < EMB) su[tid] = up[tid];
        else           sv[tid - EMB] = vp[tid - EMB];
        __syncthreads();

        int g = tid >> 4, j = tid & 15;
        #pragma unroll
        for (int mat = 0; mat < 4; ++mat) {
            const float* W = (mat == 0) ? Wui : (mat == 1) ? Wuh : (mat == 2) ? Wii : Wih;
            const float* x = (mat == 1 || mat == 2) ? su : sv;
            const float4* x4 = (const float4*)x;
            float4 xa = x4[2 * j], xb = x4[2 * j + 1];
            #pragma unroll
            for (int b = 0; b < 3; ++b) {
                int rbase = g * 24 + b * 8;            // 0..383 within mat
                float4 w0[8], w1[8];
                #pragma unroll
                for (int q = 0; q < 8; ++q) {
                    const float4* W4 = (const float4*)(W + (size_t)(rbase + q) * EMB);
                    w0[q] = W4[2 * j]; w1[q] = W4[2 * j + 1];
                }
                #pragma unroll
                for (int q = 0; q < 8; ++q) {
                    float s = w0[q].x * xa.x + w0[q].y * xa.y
                            + w0[q].z * xa.z + w0[q].w * xa.w
                            + w1[q].x * xb.x + w1[q].y * xb.y
                            + w1[q].z * xb.z + w1[q].w * xb.w;
                    s += __shfl_xor(s, 1); s += __shfl_xor(s, 2);
                    s += __shfl_xor(s, 4); s += __shfl_xor(s, 8);
                    if (j == q) gg[mat * 384 + rbase + q] = s;
                }
            }
        }
        __syncthreads();

        if (tid < EMB) {
            int e = tid;
            float r_ = sigmoidf_(gg[e] + bui[e] + gg[384 + e] + buh[e]);
            float z_ = sigmoidf_(gg[128 + e] + bui[128 + e] + gg[512 + e] + buh[128 + e]);
            float n_ = tanhf(gg[256 + e] + bui[256 + e] + r_ * (gg[640 + e] + buh[256 + e]));
            NU[(size_t)t * EMB + e] = (1.f - z_) * n_ + z_ * su[e];
        } else {
            int e = tid - EMB;
            float r_ = sigmoidf_(gg[768 + e] + bii[e] + gg[1152 + e] + bih[e]);
            float z_ = sigmoidf_(gg[896 + e] + bii[128 + e] + gg[1280 + e] + bih[128 + e]);
            float n_ = tanhf(gg[1024 + e] + bii[256 + e] + r_ * (gg[1408 + e] + bih[256 + e]));
            NV[(size_t)t * EMB + e] = (1.f - z_) * n_ + z_ * sv[e];
        }
        __threadfence();      // release: data visible device-wide
        __syncthreads();      // all threads' stores fenced
        if (tid == 0) atomicExch(&flags[t], 1);
    }
}

// ---------------------------------------------------------------------------
// Kernel 5a: gather INPUT u,v for ALL events into XAu/XAv + loss output.
// ---------------------------------------------------------------------------
__global__ __launch_bounds__(256) void gatherall_kernel(
    const float* __restrict__ U0, const float* __restrict__ V0,
    const int* __restrict__ uids, const int* __restrict__ iids,
    const int* __restrict__ prevu, const int* __restrict__ previ,
    const float* __restrict__ NU, const float* __restrict__ NV,
    float* __restrict__ XAu, float* __restrict__ XAv,
    float* __restrict__ out, int nev)
{
    int sub = threadIdx.x >> 5;
    int lane = threadIdx.x & 31;
    int t = blockIdx.x * 8 + sub;
    if (t >= nev) return;
    int pu = prevu[t], pi = previ[t];
    const float4* up = (const float4*)(pu < 0 ?
        U0 + (size_t)uids[t] * EMB : NU + (size_t)pu * EMB);
    const float4* vp = (const float4*)(pi < 0 ?
        V0 + (size_t)iids[t] * EMB : NV + (size_t)pi * EMB);
    float4 a = up[lane], c = vp[lane];
    ((float4*)(XAu + (size_t)t * EMB))[lane] = a;
    ((float4*)(XAv + (size_t)t * EMB))[lane] = c;
    float dp = a.x * c.x + a.y * c.y + a.z * c.z + a.w * c.w;
    dp += __shfl_xor(dp, 1); dp += __shfl_xor(dp, 2);
    dp += __shfl_xor(dp, 4); dp += __shfl_xor(dp, 8);
    dp += __shfl_xor(dp, 16);
    if (lane == 0) out[2 * (size_t)t] = -logf(softplusf_(dp) + 1e-10f);
}

// ---------------------------------------------------------------------------
// Kernel 5b: T1 GEMM. H1 = relu([XAu|XAv] @ T1w^T + b). K=256 in 4 chunks.
// ---------------------------------------------------------------------------
__global__ __launch_bounds__(256, 4) void t1_gemm_kernel(
    const float* __restrict__ XAu, const float* __restrict__ XAv,
    const float* __restrict__ T1w, const float* __restrict__ T1b,
    float* __restrict__ H1, int nev)
{
    __shared__ float4 Xs[1024];
    __shared__ float4 Ws[1024];
    int ev0 = blockIdx.x * 64;
    int row0 = blockIdx.y * 64;
    int tid = threadIdx.x;
    int e0 = (tid >> 4) * 4, r0 = (tid & 15) * 4;
    int sx = (e0 >> 2) & 7, sw = (r0 >> 2) & 7;
    float acc[4][4] = {};
    const float4* W4 = (const float4*)T1w;

    for (int kh = 0; kh < 4; ++kh) {
        const float4* X4 = (const float4*)((kh < 2) ? XAu : XAv);
        int khh = kh & 1;
        __syncthreads();
        #pragma unroll
        for (int p = 0; p < 4; ++p) {
            int q = p * 256 + tid;
            int r = q >> 4, c4 = q & 15;
            int sr = (r >> 2) & 7;
            Xs[r * 16 + (c4 ^ sr)] = X4[(size_t)(ev0 + r) * 32 + khh * 16 + c4];
            Ws[r * 16 + (c4 ^ sr)] = W4[(size_t)(row0 + r) * 64 + kh * 16 + c4];
        }
        __syncthreads();
        #pragma unroll 4
        for (int k4 = 0; k4 < 16; ++k4) {
            float4 xa[4], wb[4];
            #pragma unroll
            for (int i = 0; i < 4; ++i) xa[i] = Xs[(e0 + i) * 16 + (k4 ^ sx)];
            #pragma unroll
            for (int jj = 0; jj < 4; ++jj) wb[jj] = Ws[(r0 + jj) * 16 + (k4 ^ sw)];
            #pragma unroll
            for (int i = 0; i < 4; ++i) {
                #pragma unroll
                for (int jj = 0; jj < 4; ++jj) {
                    acc[i][jj] = fmaf(xa[i].x, wb[jj].x, acc[i][jj]);
                    acc[i][jj] = fmaf(xa[i].y, wb[jj].y, acc[i][jj]);
                    acc[i][jj] = fmaf(xa[i].z, wb[jj].z, acc[i][jj]);
                    acc[i][jj] = fmaf(xa[i].w, wb[jj].w, acc[i][jj]);
                }
            }
        }
    }
    int col0 = row0 + r0;
    float b0 = T1b[col0], b1 = T1b[col0 + 1], b2 = T1b[col0 + 2], b3 = T1b[col0 + 3];
    #pragma unroll
    for (int i = 0; i < 4; ++i) {
        float4 v;
        v.x = fmaxf(acc[i][0] + b0, 0.f);
        v.y = fmaxf(acc[i][1] + b1, 0.f);
        v.z = fmaxf(acc[i][2] + b2, 0.f);
        v.w = fmaxf(acc[i][3] + b3, 0.f);
        *(float4*)&H1[(size_t)(ev0 + e0 + i) * EMB + col0] = v;
    }
}

// ---------------------------------------------------------------------------
// Kernel 5c: T2 + T3 + sigmoid. 16 events per block; T2w staged in LDS.
// ---------------------------------------------------------------------------
__global__ __launch_bounds__(256) void t2t3_kernel(
    const float* __restrict__ H1,
    const float* __restrict__ T2w, const float* __restrict__ T2b,
    const float* __restrict__ T3w, const float* __restrict__ T3b,
    float* __restrict__ out, int nev)
{
    __shared__ __align__(16) float w2s[32][132];
    __shared__ __align__(16) float h1s[16][132];
    __shared__ float h2s[16][36];
    int tid = threadIdx.x;
    int ev = tid >> 4, j = tid & 15;
    int t = blockIdx.x * 16 + ev;

    {   // stage T2w (32x128)
        const float4* s2 = (const float4*)T2w;
        #pragma unroll
        for (int i = 0; i < 4; ++i) {
            int q = i * 256 + tid;
            int r = q >> 5, c4 = q & 31;
            *(float4*)&w2s[r][c4 * 4] = s2[q];
        }
    }
    {   // stage h1 (16 events x 128)
        const float4* h4 = (const float4*)(H1 + (size_t)(blockIdx.x * 16 + ev) * EMB);
        *(float4*)&h1s[ev][8 * j]     = h4[2 * j];
        *(float4*)&h1s[ev][8 * j + 4] = h4[2 * j + 1];
    }
    __syncthreads();

    float acc0 = T2b[2 * j], acc1 = T2b[2 * j + 1];
    const float4* wr0 = (const float4*)&w2s[2 * j][0];
    const float4* wr1 = (const float4*)&w2s[2 * j + 1][0];
    const float4* xh = (const float4*)&h1s[ev][0];
    #pragma unroll
    for (int k = 0; k < 32; ++k) {
        float4 x = xh[k], a = wr0[k], b = wr1[k];
        acc0 = fmaf(a.x, x.x, acc0); acc0 = fmaf(a.y, x.y, acc0);
        acc0 = fmaf(a.z, x.z, acc0); acc0 = fmaf(a.w, x.w, acc0);
        acc1 = fmaf(b.x, x.x, acc1); acc1 = fmaf(b.y, x.y, acc1);
        acc1 = fmaf(b.z, x.z, acc1); acc1 = fmaf(b.w, x.w, acc1);
    }
    h2s[ev][2 * j]     = fmaxf(acc0, 0.f);
    h2s[ev][2 * j + 1] = fmaxf(acc1, 0.f);
    __syncthreads();

    float p = T3w[2 * j] * h2s[ev][2 * j] + T3w[2 * j + 1] * h2s[ev][2 * j + 1];
    p += __shfl_xor(p, 1); p += __shfl_xor(p, 2);
    p += __shfl_xor(p, 4); p += __shfl_xor(p, 8);
    if (j == 0 && t < nev)
        out[2 * (size_t)t + 1] = sigmoidf_(p + T3b[0]);
}

// ---------------------------------------------------------------------------
extern "C" void kernel_launch(void* const* d_in, const int* in_sizes, int n_in,
                              void* d_out, int out_size, void* d_ws, size_t ws_size,
                              hipStream_t stream)
{
    const float* U0  = (const float*)d_in[0];
    const float* V0  = (const float*)d_in[1];
    const float* Wui = (const float*)d_in[2];
    const float* Wuh = (const float*)d_in[3];
    const float* bui = (const float*)d_in[4];
    const float* buh = (const float*)d_in[5];
    const float* Wii = (const float*)d_in[6];
    const float* Wih = (const float*)d_in[7];
    const float* bii = (const float*)d_in[8];
    const float* bih = (const float*)d_in[9];
    const float* T1w = (const float*)d_in[10];
    const float* T1b = (const float*)d_in[11];
    const float* T2w = (const float*)d_in[12];
    const float* T2b = (const float*)d_in[13];
    const float* T3w = (const float*)d_in[14];
    const float* T3b = (const float*)d_in[15];
    const int* uids  = (const int*)d_in[16];
    const int* iids  = (const int*)d_in[17];
    int nev = in_sizes[16];

    char* ws = (char*)d_ws;
    int* base = (int*)ws;
    int* prevu     = base;                 // MAXEV
    int* previ     = base + MAXEV;         // MAXEV
    int* l0order   = base + 2 * MAXEV;     // MAXEV
    int* tailOrder = base + 3 * MAXEV;     // MAXEV
    int* flags     = base + 4 * MAXEV;     // MAXEV
    Hdr* hdr       = (Hdr*)(base + 5 * MAXEV);
    float* NU = (float*)(ws + (128 << 10));            // 2 MB
    float* NV = NU + (size_t)MAXEV * EMB;              // 2 MB
    float* Xu = NV + (size_t)MAXEV * EMB;              // 2 MB (reused as XAu)
    float* Xv = Xu + (size_t)MAXEV * EMB;              // 2 MB (reused as XAv)
    float* Gu = Xv + (size_t)MAXEV * EMB;              // 12.6 MB (reused as H1)
    float* Gv = Gu + (size_t)MAXEV * 768;              // 12.6 MB
    float* out = (float*)d_out;

    prev_kernel<<<nev, 64, 0, stream>>>(uids, iids, prevu, previ, nev);
    setup_kernel<<<1, 1024, 0, stream>>>(prevu, previ, l0order, tailOrder, hdr, nev);
    hipMemsetAsync(flags, 0, MAXEV * sizeof(int), stream);

    gather_kernel<<<(MAXEV + 7) / 8, 256, 0, stream>>>(
        U0, V0, uids, iids, l0order, hdr, Xu, Xv);
    gate_gemm_kernel<<<dim3(MAXEV / 64, 12, 2), 256, 0, stream>>>(
        Xu, Xv, Wuh, Wii, Wui, Wih, hdr, Gu, Gv);
    combine_kernel<<<(MAXEV + 1) / 2, 256, 0, stream>>>(
        Gu, Gv, Xu, Xv, bui, buh, bii, bih, l0order, hdr, NU, NV, flags);

    // co-resident spin grid
    int nb = 0;
    (void)hipOccupancyMaxActiveBlocksPerMultiprocessor(&nb, tail_kernel, 256, 0);
    if (nb < 1) nb = 1;
    int ncu = 256;
    (void)hipDeviceGetAttribute(&ncu, hipDeviceAttributeMultiprocessorCount, 0);
    int nblk = nb * ncu;
    if (nblk > 1024) nblk = 1024;
    tail_kernel<<<nblk, 256, 0, stream>>>(
        U0, V0, Wui, Wuh, bui, buh, Wii, Wih, bii, bih,
        uids, iids, prevu, previ, tailOrder, hdr, flags, NU, NV);

    float* XAu = Xu;   // Xu/Xv dead after combine
    float* XAv = Xv;
    float* H1  = Gu;   // Gu dead after combine
    gatherall_kernel<<<(nev + 7) / 8, 256, 0, stream>>>(
        U0, V0, uids, iids, prevu, previ, NU, NV, XAu, XAv, out, nev);
    t1_gemm_kernel<<<dim3((nev + 63) / 64, 2), 256, 0, stream>>>(
        XAu, XAv, T1w, T1b, H1, nev);
    t2t3_kernel<<<(nev + 15) / 16, 256, 0, stream>>>(
        H1, T2w, T2b, T3w, T3b, out, nev);
}